// Round 14
// baseline (1203.882 us; speedup 1.0000x reference)
//
#include <hip/hip_runtime.h>
#include <hip/hip_bf16.h>

constexpr int Ej  = 294912;  // total edges
constexpr int EPG = 1152;    // edges per graph
constexpr int WC2 = 144;     // fused-GEMM cols per head: A64 | V64 | r8:8 | cD | cS | pad6
constexpr int SPF = 132;     // scores fp32 row stride (floats); bf16 Wmat row lives at hw d*264
constexpr int HBS = 72;      // hB / A-matrix bf16 row stride (halfwords)
constexpr int VTS = 136;     // Vt bf16 row stride (halfwords)

typedef __attribute__((ext_vector_type(8))) short short8;   // 8 bf16 (MFMA A/B frag)
typedef __attribute__((ext_vector_type(4))) float f32x4;    // MFMA C/D frag

// fp32 -> bf16 bits, round-to-nearest-even
__device__ __forceinline__ unsigned short f2bf(float f) {
  unsigned u = __float_as_uint(f);
  u += 0x7FFFu + ((u >> 16) & 1u);
  return (unsigned short)(u >> 16);
}
__device__ __forceinline__ float bf2f(unsigned short b) {
  return __uint_as_float(((unsigned)b) << 16);
}
// DPP helpers: reductions within aligned 8-lane groups, pure VALU (no LDS pipe).
template <int CTRL>
__device__ __forceinline__ float dppf(float x) {
  return __int_as_float(__builtin_amdgcn_update_dpp(0, __float_as_int(x), CTRL, 0xf, 0xf, true));
}
// 0xB1 = quad_perm xor1, 0x4E = quad_perm xor2, 0x141 = row_half_mirror (i<->7-i in 8)
__device__ __forceinline__ float grp8_sum(float x) {
  x += dppf<0xB1>(x); x += dppf<0x4E>(x); x += dppf<0x141>(x); return x;
}
__device__ __forceinline__ float grp8_max(float x) {
  x = fmaxf(x, dppf<0xB1>(x)); x = fmaxf(x, dppf<0x4E>(x)); x = fmaxf(x, dppf<0x141>(x));
  return x;
}
// 64-lane sum via DPP. Result valid in lane 63.
__device__ __forceinline__ float wave_red_sum(float x) {
  x += __int_as_float(__builtin_amdgcn_update_dpp(0, __float_as_int(x), 0x111, 0xf, 0xf, true));
  x += __int_as_float(__builtin_amdgcn_update_dpp(0, __float_as_int(x), 0x112, 0xf, 0xf, true));
  x += __int_as_float(__builtin_amdgcn_update_dpp(0, __float_as_int(x), 0x114, 0xf, 0xf, true));
  x += __int_as_float(__builtin_amdgcn_update_dpp(0, __float_as_int(x), 0x118, 0xf, 0xf, true));
  x += __int_as_float(__builtin_amdgcn_update_dpp(0, __float_as_int(x), 0x142, 0xf, 0xf, true));
  x += __int_as_float(__builtin_amdgcn_update_dpp(0, __float_as_int(x), 0x143, 0xf, 0xf, true));
  return x;
}

// G[l][h][a][c] = sum_d W_edge[a,d]*We_l[d][h64+c];  bb[l][h][c] = be + b_edge@We
__global__ void k_prep2(const float* __restrict__ We, const float* __restrict__ be,
                        const float* __restrict__ W_edge, const float* __restrict__ b_edge,
                        float* __restrict__ G, float* __restrict__ bb) {
  int tid = blockIdx.x * 256 + threadIdx.x;  // 8192 + 1024
  if (tid < 8192) {
    int l = tid >> 11, rem = tid & 2047;
    int hh = rem >> 9, a = (rem >> 6) & 7, c = rem & 63;
    float acc = 0.f;
#pragma unroll 8
    for (int d = 0; d < 64; ++d)
      acc += W_edge[a * 64 + d] * We[l * 16384 + d * 256 + hh * 64 + c];
    G[tid] = acc;
  } else if (tid < 9216) {
    int t = tid - 8192;
    int l = t >> 8, rem = t & 255;
    int hh = rem >> 6, c = rem & 63;
    float acc = be[l * 256 + hh * 64 + c];
#pragma unroll 8
    for (int d = 0; d < 64; ++d)
      acc += b_edge[d] * We[l * 16384 + d * 256 + hh * 64 + c];
    bb[t] = acc;
  }
}

// WcatT [lh][col][kk] bf16 + bcatT fp32.  (see earlier rounds for column semantics)
__global__ void __launch_bounds__(256) k_prepW(
    const float* __restrict__ Wq, const float* __restrict__ bq,
    const float* __restrict__ Wk, const float* __restrict__ bk,
    const float* __restrict__ Wv, const float* __restrict__ bv,
    const float* __restrict__ Gbuf, const float* __restrict__ bbuf,
    unsigned short* __restrict__ WcatT, float* __restrict__ bcatT) {
  int t = blockIdx.x * 256 + threadIdx.x;  // 16*144*64
  if (t >= 16 * WC2 * 64) return;
  int kk = t & 63;
  int col = (t >> 6) % WC2;
  int lh = t / (WC2 * 64);
  int h = lh & 3, l = lh >> 2;
  const float* Wq_l = Wq + l * 16384;
  const float* Wk_l = Wk + l * 16384;
  const float* bq_l = bq + l * 256;
  const float* bk_l = bk + l * 256;
  float w = 0.f, bias = 0.f;
  if (col < 64) {
    float s = 0.f;
#pragma unroll 8
    for (int i = 0; i < 64; ++i)
      s += Wq_l[kk * 256 + h * 64 + i] * Wk_l[col * 256 + h * 64 + i];
    w = 0.125f * s;
  } else if (col < 128) {
    int j = col - 64;
    w = Wv[l * 16384 + kk * 256 + h * 64 + j];
    bias = bv[l * 256 + h * 64 + j];
  } else if (col < 136) {
    int a = col - 128;
    const float* Grow = Gbuf + l * 2048 + h * 512 + a * 64;
    float s = 0.f, sb = 0.f;
#pragma unroll 8
    for (int i = 0; i < 64; ++i) {
      s  += Wq_l[kk * 256 + h * 64 + i] * Grow[i];
      sb += bq_l[h * 64 + i] * Grow[i];
    }
    w = 0.125f * s; bias = 0.125f * sb;
  } else if (col == 136) {
    float s = 0.f, sb = 0.f;
#pragma unroll 8
    for (int i = 0; i < 64; ++i) {
      float bkb = bk_l[h * 64 + i] + bbuf[l * 256 + h * 64 + i];
      s  += Wq_l[kk * 256 + h * 64 + i] * bkb;
      sb += bq_l[h * 64 + i] * bkb;
    }
    w = 0.125f * s; bias = 0.125f * sb;
  } else if (col == 137) {
    float s = 0.f;
#pragma unroll 8
    for (int i = 0; i < 64; ++i)
      s += Wk_l[kk * 256 + h * 64 + i] * bq_l[h * 64 + i];
    w = 0.125f * s;
  }
  WcatT[(size_t)(lh * WC2 + col) * 64 + kk] = f2bf(w);
  if (kk == 0) bcatT[lh * WC2 + col] = bias;
}

// Sort each graph's edges by dst (dup-rank per (dst,src) via 16K cursor). Emits
// sortedSR (src | duprank<<8 | dst<<16), sortedEA, offs[g][129]. LDS 66 KB.
__global__ void __launch_bounds__(256) k_sort(const int* __restrict__ ei,
                                              const float* __restrict__ edge_attr,
                                              int* __restrict__ sortedSR,
                                              float* __restrict__ sortedEA,
                                              int* __restrict__ offs) {
  __shared__ unsigned cursor[16384];  // (dst,src) dup-rank, 64 KB
  __shared__ unsigned cnt[128];       // per-dst count -> scatter cursor
  __shared__ unsigned base[129];
  int g = blockIdx.x, tid = threadIdx.x;
  for (int i = tid; i < 16384; i += 256) cursor[i] = 0u;
  if (tid < 128) cnt[tid] = 0u;
  __syncthreads();
  for (int e = tid; e < EPG; e += 256) {
    int d = ei[Ej + g * EPG + e] - g * 128;
    atomicAdd(&cnt[d], 1u);
  }
  __syncthreads();
  if (tid == 0) {
    unsigned run = 0;
    for (int j = 0; j < 128; ++j) { base[j] = run; run += cnt[j]; }
    base[128] = run;
  }
  __syncthreads();
  if (tid < 128) { offs[g * 129 + tid] = (int)base[tid]; cnt[tid] = base[tid]; }
  if (tid == 0) offs[g * 129 + 128] = EPG;
  __syncthreads();
  for (int e = tid; e < EPG; e += 256) {
    int s = ei[g * EPG + e] - g * 128;
    int d = ei[Ej + g * EPG + e] - g * 128;
    unsigned pos = atomicAdd(&cnt[d], 1u);
    unsigned r = atomicAdd(&cursor[d * 128 + s], 1u);
    sortedSR[g * EPG + pos] = s | ((int)min(r, 3u) << 8) | (d << 16);
    const float4* ep = (const float4*)(edge_attr + ((size_t)g * EPG + e) * 8);
    float4* op = (float4*)(sortedEA + ((size_t)g * EPG + pos) * 8);
    op[0] = ep[0]; op[1] = ep[1];
  }
}

// One block per graph, 512 threads (8 waves, 2/SIMD — the only spill-free config).
// r10 base + LDS-instruction diet: (1) update-phase skip GEMM uses TRANSPOSED Wskip in SS
// and float4 dots (2048 scalar -> 320 float4 LDS reads/thread/layer, fp32 exact);
// (2) t8L stride 9->12 (16B rows): PD stores + P5 reads via float4 (128 scalar -> 32 f4).
// 3 barriers/head. LDS 154112 B -> 1 block/CU.
__global__ void __launch_bounds__(512, 2) k_fused(
    const float* __restrict__ x, const float* __restrict__ W_node, const float* __restrict__ b_node,
    const unsigned short* __restrict__ WcatT, const float* __restrict__ bcatT,
    const int* __restrict__ sortedSR, const float* __restrict__ sortedEA,
    const int* __restrict__ offs,
    const float* __restrict__ Gbuf, const float* __restrict__ bbuf,
    const float* __restrict__ Wskip, const float* __restrict__ bskip,
    const float* __restrict__ Wd, const float* __restrict__ bd,
    const float* __restrict__ Wo, const float* __restrict__ bo,
    float* __restrict__ out) {
  __shared__ float SS[128 * SPF];           // 67584 B: scores fp32 / Wmat bf16 / WskT (update)
  __shared__ float h32[128 * 68];           // 34816 B: resident fp32 h
  __shared__ unsigned short hB[128 * HBS];  // 18432 B: bf16 h
  __shared__ unsigned short AV[128 * HBS];  // 18432 B: A-matrix (P0-P1) then Vt 64xVTS (PD-P5)
  __shared__ float r8L[128 * 8];            // 4096
  __shared__ float t8L[128 * 12];           // 6144 (16B-aligned rows)
  __shared__ float sL[128];                 // 512
  __shared__ float cDL[128];                // 512
  __shared__ float cSL[128];                // 512
  __shared__ float GhL[512];                // 2048
  __shared__ float vembL[256];              // 1024

  int g = blockIdx.x, tid = threadIdx.x;
  int lane = tid & 63, m16 = lane & 15, quad = lane >> 4, wv = tid >> 6;  // wv 0..7
  const int m0 = wv * 16;  // this wave's m-strip / dst-strip everywhere
  const int gE = g * EPG;

  // node encoder -> h32
  for (int idx = tid; idx < 8192; idx += 512) {
    int n = idx >> 6, c = idx & 63;
    const float* xr = x + (size_t)(g * 128 + n) * 16;
    float acc = b_node[c];
#pragma unroll
    for (int d = 0; d < 16; ++d) acc += xr[d] * W_node[d * 64 + c];
    h32[n * 68 + c] = acc;
  }

  // per-dst segments: 8-lane group handles dsts dD0 and dD0+64
  const int dD0 = tid >> 3, sub = tid & 7;
  const int dD1 = dD0 + 64;
  const int ofs0 = offs[g * 129 + dD0];
  const int ofs1 = offs[g * 129 + dD1];
  const int dsw = (dD0 & 7) << 4;  // XOR swizzle; same for dD1
  // sortedSR entries are layer/head-invariant: load ONCE into persistent named regs
  int sr0_0, sr0_1, sr0_2, sr0_3, sr0_4, sr1_0, sr1_1, sr1_2, sr1_3, sr1_4;
  {
    int cnt0 = offs[g * 129 + dD0 + 1] - ofs0;
    int cnt1 = offs[g * 129 + dD1 + 1] - ofs1;
    int p = sub;
    sr0_0 = (p      < cnt0) ? sortedSR[gE + ofs0 + p]      : -1;
    sr0_1 = (p + 8  < cnt0) ? sortedSR[gE + ofs0 + p + 8]  : -1;
    sr0_2 = (p + 16 < cnt0) ? sortedSR[gE + ofs0 + p + 16] : -1;
    sr0_3 = (p + 24 < cnt0) ? sortedSR[gE + ofs0 + p + 24] : -1;
    sr0_4 = (p + 32 < cnt0) ? sortedSR[gE + ofs0 + p + 32] : -1;
    sr1_0 = (p      < cnt1) ? sortedSR[gE + ofs1 + p]      : -1;
    sr1_1 = (p + 8  < cnt1) ? sortedSR[gE + ofs1 + p + 8]  : -1;
    sr1_2 = (p + 16 < cnt1) ? sortedSR[gE + ofs1 + p + 16] : -1;
    sr1_3 = (p + 24 < cnt1) ? sortedSR[gE + ofs1 + p + 24] : -1;
    sr1_4 = (p + 32 < cnt1) ? sortedSR[gE + ofs1 + p + 32] : -1;
  }
  __syncthreads();

  for (int l = 0; l < 4; ++l) {
    // ---- stage hB = bf16(h32): 2 slices of 64 rows
    {
      int row = tid >> 3, c8 = tid & 7;
#pragma unroll
      for (int s2 = 0; s2 < 2; ++s2) {
        int rr = row + s2 * 64;
        const float* hr = &h32[rr * 68 + c8 * 8];
        float4 a0 = *(const float4*)hr, a1 = *(const float4*)(hr + 4);
        uint4 hp;
        hp.x = f2bf(a0.x) | ((unsigned)f2bf(a0.y) << 16);
        hp.y = f2bf(a0.z) | ((unsigned)f2bf(a0.w) << 16);
        hp.z = f2bf(a1.x) | ((unsigned)f2bf(a1.y) << 16);
        hp.w = f2bf(a1.z) | ((unsigned)f2bf(a1.w) << 16);
        *(uint4*)&hB[rr * HBS + c8 * 8] = hp;
      }
    }
    f32x4 accP5_0 = {0.f, 0.f, 0.f, 0.f};
    f32x4 accP5_1 = {0.f, 0.f, 0.f, 0.f};
    f32x4 accP5_2 = {0.f, 0.f, 0.f, 0.f};
    f32x4 accP5_3 = {0.f, 0.f, 0.f, 0.f};
    float4 wsk0, wsk1;
    __syncthreads();  // hB ready (stable for whole layer)

    for (int h = 0; h < 4; ++h) {
      const int lh = l * 4 + h;
      // ---- P0: qkv GEMM; WT/bias direct from global (L2-hot). 9 n-tiles per wave.
      const unsigned short* WTg = WcatT + (size_t)lh * (WC2 * 64);
      const float* bcTl = bcatT + (size_t)lh * WC2;
      f32x4 vf0, vf1, vf2, vf3;
      {
        const short8 ha0 = *(const short8*)&hB[(m0 + m16) * HBS + quad * 8];
        const short8 ha1 = *(const short8*)&hB[(m0 + m16) * HBS + 32 + quad * 8];
#pragma unroll
        for (int nt = 0; nt < 9; ++nt) {
          int n0 = nt * 16;
          const unsigned short* wb = WTg + (size_t)(n0 + m16) * 64 + quad * 8;
          const short8 b0 = *(const short8*)wb;
          const short8 b1 = *(const short8*)(wb + 32);
          float bias = bcTl[n0 + m16];
          f32x4 acc = {bias, bias, bias, bias};
          acc = __builtin_amdgcn_mfma_f32_16x16x32_bf16(ha0, b0, acc, 0, 0, 0);
          acc = __builtin_amdgcn_mfma_f32_16x16x32_bf16(ha1, b1, acc, 0, 0, 0);
          if (nt < 4) {
#pragma unroll
            for (int r = 0; r < 4; ++r)
              AV[(m0 + quad * 4 + r) * HBS + n0 + m16] = f2bf(acc[r]);
          } else if (nt == 4) {
            vf0 = acc;
          } else if (nt == 5) {
            vf1 = acc;
          } else if (nt == 6) {
            vf2 = acc;
          } else if (nt == 7) {
            vf3 = acc;
          } else {  // nt == 8: r8 | cD | cS
            if (m16 < 8) {
#pragma unroll
              for (int r = 0; r < 4; ++r) r8L[(m0 + quad * 4 + r) * 8 + m16] = acc[r];
            } else if (m16 == 8) {
#pragma unroll
              for (int r = 0; r < 4; ++r) cDL[m0 + quad * 4 + r] = acc[r];
            } else if (m16 == 9) {
#pragma unroll
              for (int r = 0; r < 4; ++r) cSL[m0 + quad * 4 + r] = acc[r];
            }
          }
        }
      }
      // NO barrier: P1 reads only own-wave AV rows (DS in-order) + stable hB.

      // ---- P1: scores MFMA -> SS (col XOR-swizzled) || GhL stage
      {
        GhL[tid] = Gbuf[l * 2048 + h * 512 + tid];
        const short8 sa0 = *(const short8*)&AV[(m0 + m16) * HBS + quad * 8];
        const short8 sa1 = *(const short8*)&AV[(m0 + m16) * HBS + 32 + quad * 8];
#pragma unroll
        for (int t = 0; t < 8; ++t) {
          int src0 = t * 16;
          const short8 b0 = *(const short8*)&hB[(src0 + m16) * HBS + quad * 8];
          const short8 b1 = *(const short8*)&hB[(src0 + m16) * HBS + 32 + quad * 8];
          f32x4 acc = {0.f, 0.f, 0.f, 0.f};
          acc = __builtin_amdgcn_mfma_f32_16x16x32_bf16(sa0, b0, acc, 0, 0, 0);
          acc = __builtin_amdgcn_mfma_f32_16x16x32_bf16(sa1, b1, acc, 0, 0, 0);
#pragma unroll
          for (int r = 0; r < 4; ++r) {
            int row = m0 + quad * 4 + r;
            SS[row * SPF + ((src0 + m16) ^ ((row & 7) << 4))] = acc[r];
          }
        }
      }
      __syncthreads();  // scores/cSL/r8L/cDL visible cross-wave for PD

      // ---- PD: V-deposit; two per-dst softmaxes; guarded transient ea loads (r10 form)
      {
#pragma unroll
        for (int r = 0; r < 4; ++r) AV[(m16) * VTS + m0 + quad * 4 + r] = f2bf(vf0[r]);
#pragma unroll
        for (int r = 0; r < 4; ++r) AV[(16 + m16) * VTS + m0 + quad * 4 + r] = f2bf(vf1[r]);
#pragma unroll
        for (int r = 0; r < 4; ++r) AV[(32 + m16) * VTS + m0 + quad * 4 + r] = f2bf(vf2[r]);
#pragma unroll
        for (int r = 0; r < 4; ++r) AV[(48 + m16) * VTS + m0 + quad * 4 + r] = f2bf(vf3[r]);
        unsigned short* Wu = (unsigned short*)SS;

        // batched LDS loads (unpredicated; invalid slots read valid-but-unused addrs)
        int s00 = sr0_0 & 127, s01 = sr0_1 & 127, s02 = sr0_2 & 127, s03 = sr0_3 & 127,
            s04 = sr0_4 & 127;
        int s10 = sr1_0 & 127, s11 = sr1_1 & 127, s12 = sr1_2 & 127, s13 = sr1_3 & 127,
            s14 = sr1_4 & 127;
        float sc00 = SS[dD0 * SPF + (s00 ^ dsw)], sc01 = SS[dD0 * SPF + (s01 ^ dsw)],
              sc02 = SS[dD0 * SPF + (s02 ^ dsw)], sc03 = SS[dD0 * SPF + (s03 ^ dsw)],
              sc04 = SS[dD0 * SPF + (s04 ^ dsw)];
        float sc10 = SS[dD1 * SPF + (s10 ^ dsw)], sc11 = SS[dD1 * SPF + (s11 ^ dsw)],
              sc12 = SS[dD1 * SPF + (s12 ^ dsw)], sc13 = SS[dD1 * SPF + (s13 ^ dsw)],
              sc14 = SS[dD1 * SPF + (s14 ^ dsw)];
        float cs00 = cSL[s00], cs01 = cSL[s01], cs02 = cSL[s02], cs03 = cSL[s03],
              cs04 = cSL[s04];
        float cs10 = cSL[s10], cs11 = cSL[s11], cs12 = cSL[s12], cs13 = cSL[s13],
              cs14 = cSL[s14];
        float cD0 = cDL[dD0], cD1 = cDL[dD1];
        float4 r8a0 = *(const float4*)&r8L[dD0 * 8];
        float4 r8b0 = *(const float4*)&r8L[dD0 * 8 + 4];
        float4 r8a1 = *(const float4*)&r8L[dD1 * 8];
        float4 r8b1 = *(const float4*)&r8L[dD1 * 8 + 4];

        // alphas: inline dot(ea, r8[dst]) with transient guarded ea loads
        float al00 = -3.4e38f, al01 = -3.4e38f, al02 = -3.4e38f, al03 = -3.4e38f,
              al04 = -3.4e38f;
        float al10 = -3.4e38f, al11 = -3.4e38f, al12 = -3.4e38f, al13 = -3.4e38f,
              al14 = -3.4e38f;
#define ADOT(AL, SR, OFS, IT, SCV, CSV, CDV, R8A, R8B)                                 \
        if (SR >= 0) {                                                                 \
          const float* ep = sortedEA + (size_t)(gE + (OFS) + sub + (IT)*8) * 8;        \
          float4 p0 = *(const float4*)ep;                                              \
          float4 p1 = *(const float4*)(ep + 4);                                        \
          AL = SCV + CDV + CSV                                                         \
             + p0.x * R8A.x + p0.y * R8A.y + p0.z * R8A.z + p0.w * R8A.w               \
             + p1.x * R8B.x + p1.y * R8B.y + p1.z * R8B.z + p1.w * R8B.w;              \
        }
        ADOT(al00, sr0_0, ofs0, 0, sc00, cs00, cD0, r8a0, r8b0)
        ADOT(al01, sr0_1, ofs0, 1, sc01, cs01, cD0, r8a0, r8b0)
        ADOT(al02, sr0_2, ofs0, 2, sc02, cs02, cD0, r8a0, r8b0)
        ADOT(al03, sr0_3, ofs0, 3, sc03, cs03, cD0, r8a0, r8b0)
        ADOT(al04, sr0_4, ofs0, 4, sc04, cs04, cD0, r8a0, r8b0)
        ADOT(al10, sr1_0, ofs1, 0, sc10, cs10, cD1, r8a1, r8b1)
        ADOT(al11, sr1_1, ofs1, 1, sc11, cs11, cD1, r8a1, r8b1)
        ADOT(al12, sr1_2, ofs1, 2, sc12, cs12, cD1, r8a1, r8b1)
        ADOT(al13, sr1_3, ofs1, 3, sc13, cs13, cD1, r8a1, r8b1)
        ADOT(al14, sr1_4, ofs1, 4, sc14, cs14, cD1, r8a1, r8b1)
#undef ADOT
        float mx0 = grp8_max(fmaxf(fmaxf(fmaxf(al00, al01), fmaxf(al02, al03)), al04));
        float mx1 = grp8_max(fmaxf(fmaxf(fmaxf(al10, al11), fmaxf(al12, al13)), al14));

        // exp + transient ea reload + unnormalized t8 accum (no LDS stores yet)
        float t8a0 = 0.f, t8a1 = 0.f, t8a2 = 0.f, t8a3 = 0.f, t8a4 = 0.f, t8a5 = 0.f,
              t8a6 = 0.f, t8a7 = 0.f;
        float t8b0 = 0.f, t8b1 = 0.f, t8b2 = 0.f, t8b3 = 0.f, t8b4 = 0.f, t8b5 = 0.f,
              t8b6 = 0.f, t8b7 = 0.f;
        float e00 = 0.f, e01 = 0.f, e02 = 0.f, e03 = 0.f, e04 = 0.f;
        float e10 = 0.f, e11 = 0.f, e12 = 0.f, e13 = 0.f, e14 = 0.f;
#define EXPT8(E, SR, OFS, IT, AL, MX, T0, T1, T2, T3, T4, T5, T6, T7)                  \
        if (SR >= 0) {                                                                 \
          E = __expf(AL - MX);                                                         \
          const float* ep = sortedEA + (size_t)(gE + (OFS) + sub + (IT)*8) * 8;        \
          float4 p0 = *(const float4*)ep;                                              \
          float4 p1 = *(const float4*)(ep + 4);                                        \
          T0 += E * p0.x; T1 += E * p0.y; T2 += E * p0.z; T3 += E * p0.w;              \
          T4 += E * p1.x; T5 += E * p1.y; T6 += E * p1.z; T7 += E * p1.w;              \
        }
        EXPT8(e00, sr0_0, ofs0, 0, al00, mx0, t8a0, t8a1, t8a2, t8a3, t8a4, t8a5, t8a6, t8a7)
        EXPT8(e01, sr0_1, ofs0, 1, al01, mx0, t8a0, t8a1, t8a2, t8a3, t8a4, t8a5, t8a6, t8a7)
        EXPT8(e02, sr0_2, ofs0, 2, al02, mx0, t8a0, t8a1, t8a2, t8a3, t8a4, t8a5, t8a6, t8a7)
        EXPT8(e03, sr0_3, ofs0, 3, al03, mx0, t8a0, t8a1, t8a2, t8a3, t8a4, t8a5, t8a6, t8a7)
        EXPT8(e04, sr0_4, ofs0, 4, al04, mx0, t8a0, t8a1, t8a2, t8a3, t8a4, t8a5, t8a6, t8a7)
        EXPT8(e10, sr1_0, ofs1, 0, al10, mx1, t8b0, t8b1, t8b2, t8b3, t8b4, t8b5, t8b6, t8b7)
        EXPT8(e11, sr1_1, ofs1, 1, al11, mx1, t8b0, t8b1, t8b2, t8b3, t8b4, t8b5, t8b6, t8b7)
        EXPT8(e12, sr1_2, ofs1, 2, al12, mx1, t8b0, t8b1, t8b2, t8b3, t8b4, t8b5, t8b6, t8b7)
        EXPT8(e13, sr1_3, ofs1, 3, al13, mx1, t8b0, t8b1, t8b2, t8b3, t8b4, t8b5, t8b6, t8b7)
        EXPT8(e14, sr1_4, ofs1, 4, al14, mx1, t8b0, t8b1, t8b2, t8b3, t8b4, t8b5, t8b6, t8b7)
#undef EXPT8
        float s0 = grp8_sum(e00 + e01 + e02 + e03 + e04);
        float s1 = grp8_sum(e10 + e11 + e12 + e13 + e14);
        t8a0 = grp8_sum(t8a0); t8a1 = grp8_sum(t8a1); t8a2 = grp8_sum(t8a2);
        t8a3 = grp8_sum(t8a3); t8a4 = grp8_sum(t8a4); t8a5 = grp8_sum(t8a5);
        t8a6 = grp8_sum(t8a6); t8a7 = grp8_sum(t8a7);
        t8b0 = grp8_sum(t8b0); t8b1 = grp8_sum(t8b1); t8b2 = grp8_sum(t8b2);
        t8b3 = grp8_sum(t8b3); t8b4 = grp8_sum(t8b4); t8b5 = grp8_sum(t8b5);
        t8b6 = grp8_sum(t8b6); t8b7 = grp8_sum(t8b7);
        float inv0 = 1.f / fmaxf(s0, 1e-16f);
        float inv1 = 1.f / fmaxf(s1, 1e-16f);

        // stores: t8L (float4, stride 12) / sL, then zero rows, then scatter
        if (sub == 0) {
          *(float4*)&t8L[dD0 * 12] =
              make_float4(t8a0 * inv0, t8a1 * inv0, t8a2 * inv0, t8a3 * inv0);
          *(float4*)&t8L[dD0 * 12 + 4] =
              make_float4(t8a4 * inv0, t8a5 * inv0, t8a6 * inv0, t8a7 * inv0);
          sL[dD0] = s0;
          *(float4*)&t8L[dD1 * 12] =
              make_float4(t8b0 * inv1, t8b1 * inv1, t8b2 * inv1, t8b3 * inv1);
          *(float4*)&t8L[dD1 * 12 + 4] =
              make_float4(t8b4 * inv1, t8b5 * inv1, t8b6 * inv1, t8b7 * inv1);
          sL[dD1] = s1;
        }
        int rowb0 = dD0 * 264, rowb1 = dD1 * 264;
        int z0 = (sub * 16) ^ dsw;
        uint4 zz = make_uint4(0u, 0u, 0u, 0u);
        *(uint4*)&Wu[rowb0 + z0] = zz;
        *(uint4*)&Wu[rowb0 + z0 + 8] = zz;
        *(uint4*)&Wu[rowb1 + z0] = zz;
        *(uint4*)&Wu[rowb1 + z0 + 8] = zz;
        bool dup = false;
#define SCAT(SR, E, INV, ROWB)                                                         \
        if (SR >= 0) {                                                                 \
          int rk = (SR >> 8) & 3;                                                      \
          dup |= (rk != 0);                                                            \
          if (rk == 0) Wu[(ROWB) + (((SR) & 127) ^ dsw)] = f2bf((E) * (INV));          \
        }
        SCAT(sr0_0, e00, inv0, rowb0) SCAT(sr0_1, e01, inv0, rowb0)
        SCAT(sr0_2, e02, inv0, rowb0) SCAT(sr0_3, e03, inv0, rowb0)
        SCAT(sr0_4, e04, inv0, rowb0)
        SCAT(sr1_0, e10, inv1, rowb1) SCAT(sr1_1, e11, inv1, rowb1)
        SCAT(sr1_2, e12, inv1, rowb1) SCAT(sr1_3, e13, inv1, rowb1)
        SCAT(sr1_4, e14, inv1, rowb1)
#undef SCAT
        if (__any(dup)) {  // rare duplicate (dst,src): rank-ordered accumulate
#pragma unroll
          for (int rk = 1; rk < 4; ++rk) {
#define DUPA(SR, E, INV, ROWB)                                                         \
            if (SR >= 0 && (((SR >> 8) & 3) == rk)) {                                  \
              int sl = (ROWB) + (((SR) & 127) ^ dsw);                                  \
              Wu[sl] = f2bf(bf2f(Wu[sl]) + (E) * (INV));                               \
            }
            DUPA(sr0_0, e00, inv0, rowb0) DUPA(sr0_1, e01, inv0, rowb0)
            DUPA(sr0_2, e02, inv0, rowb0) DUPA(sr0_3, e03, inv0, rowb0)
            DUPA(sr0_4, e04, inv0, rowb0)
            DUPA(sr1_0, e10, inv1, rowb1) DUPA(sr1_1, e11, inv1, rowb1)
            DUPA(sr1_2, e12, inv1, rowb1) DUPA(sr1_3, e13, inv1, rowb1)
            DUPA(sr1_4, e14, inv1, rowb1)
#undef DUPA
          }
        }
      }
      __syncthreads();

      // ---- P5: accP5 += Wmat@Vt (MFMA, 4 col-tiles) + t8@G + (s>0)*bb (t8 via float4)
      {
        if (h == 3) {
          wsk0 = ((const float4*)(Wskip + (size_t)l * 4096))[tid];
          wsk1 = ((const float4*)(Wskip + (size_t)l * 4096))[512 + tid];
        }
        const unsigned short* Wu = (const unsigned short*)SS;
        int row0 = m0 + m16;
        short8 a_[4];
#pragma unroll
        for (int ks = 0; ks < 4; ++ks)
          a_[ks] = *(const short8*)&Wu[row0 * 264 + (((ks * 32) + quad * 8) ^ ((row0 & 7) << 4))];
#pragma unroll
        for (int t2 = 0; t2 < 4; ++t2) {
          int c0 = t2 * 16;
          f32x4 acc = (t2 == 0) ? accP5_0 : (t2 == 1) ? accP5_1 : (t2 == 2) ? accP5_2 : accP5_3;
#pragma unroll
          for (int ks = 0; ks < 4; ++ks) {
            const short8 b = *(const short8*)&AV[(c0 + m16) * VTS + ks * 32 + quad * 8];
            acc = __builtin_amdgcn_mfma_f32_16x16x32_bf16(a_[ks], b, acc, 0, 0, 0);
          }
          int col = c0 + m16;
          float bbv = bbuf[l * 256 + h * 64 + col];
          float gcol[8];
#pragma unroll
          for (int a8 = 0; a8 < 8; ++a8) gcol[a8] = GhL[a8 * 64 + col];
#pragma unroll
          for (int r = 0; r < 4; ++r) {
            int row = m0 + quad * 4 + r;
            float4 ta = *(const float4*)&t8L[row * 12];
            float4 tb = *(const float4*)&t8L[row * 12 + 4];
            float add = (sL[row] > 0.f) ? bbv : 0.f;
            add += ta.x * gcol[0] + ta.y * gcol[1] + ta.z * gcol[2] + ta.w * gcol[3]
                 + tb.x * gcol[4] + tb.y * gcol[5] + tb.z * gcol[6] + tb.w * gcol[7];
            acc[r] += add;
          }
          if (t2 == 0) accP5_0 = acc;
          else if (t2 == 1) accP5_1 = acc;
          else if (t2 == 2) accP5_2 = acc;
          else accP5_3 = acc;
        }
      }
      __syncthreads();
    }  // heads

    // ---- update: stage Wskip TRANSPOSED into SS (SST[c][d], stride 68);
    //      skip = float4 dot of contiguous h32 row and SST col (fp32 exact);
    //      out = 0.25*acc + skip + bskip ; vemb ; h += out (own rows, no extra barrier)
    {
      int dA = tid >> 4, cA = (tid & 15) * 4;
      SS[(cA + 0) * 68 + dA] = wsk0.x;
      SS[(cA + 1) * 68 + dA] = wsk0.y;
      SS[(cA + 2) * 68 + dA] = wsk0.z;
      SS[(cA + 3) * 68 + dA] = wsk0.w;
      int dB = 32 + dA;
      SS[(cA + 0) * 68 + dB] = wsk1.x;
      SS[(cA + 1) * 68 + dB] = wsk1.y;
      SS[(cA + 2) * 68 + dB] = wsk1.z;
      SS[(cA + 3) * 68 + dB] = wsk1.w;
    }
    __syncthreads();  // SST staged (cross-wave)
    {
      float bs0 = bskip[l * 64 + m16];
      float bs1 = bskip[l * 64 + 16 + m16];
      float bs2 = bskip[l * 64 + 32 + m16];
      float bs3 = bskip[l * 64 + 48 + m16];
      const float* w0 = &SS[(m16) * 68];
      const float* w1 = &SS[(16 + m16) * 68];
      const float* w2 = &SS[(32 + m16) * 68];
      const float* w3 = &SS[(48 + m16) * 68];
#pragma unroll
      for (int r = 0; r < 4; ++r) {
        int row = m0 + quad * 4 + r;
        const float* hr = &h32[row * 68];
        float s0 = bs0, s1 = bs1, s2 = bs2, s3 = bs3;
#pragma unroll
        for (int j = 0; j < 16; ++j) {
          float4 hv = *(const float4*)(hr + j * 4);
          float4 wa = *(const float4*)(w0 + j * 4);
          float4 wb = *(const float4*)(w1 + j * 4);
          float4 wc = *(const float4*)(w2 + j * 4);
          float4 wd = *(const float4*)(w3 + j * 4);
          s0 += hv.x * wa.x + hv.y * wa.y + hv.z * wa.z + hv.w * wa.w;
          s1 += hv.x * wb.x + hv.y * wb.y + hv.z * wb.z + hv.w * wb.w;
          s2 += hv.x * wc.x + hv.y * wc.y + hv.z * wc.z + hv.w * wc.w;
          s3 += hv.x * wd.x + hv.y * wd.y + hv.z * wd.z + hv.w * wd.w;
        }
        float o0 = accP5_0[r] * 0.25f + s0;
        float o1 = accP5_1[r] * 0.25f + s1;
        float o2 = accP5_2[r] * 0.25f + s2;
        float o3 = accP5_3[r] * 0.25f + s3;
        float hn0 = o0 + h32[row * 68 + m16];
        float hn1 = o1 + h32[row * 68 + 16 + m16];
        float hn2 = o2 + h32[row * 68 + 32 + m16];
        float hn3 = o3 + h32[row * 68 + 48 + m16];
        h32[row * 68 + m16] = hn0;
        h32[row * 68 + 16 + m16] = hn1;
        h32[row * 68 + 32 + m16] = hn2;
        h32[row * 68 + 48 + m16] = hn3;
        if (row == 127) {
          vembL[l * 64 + m16] = o0;
          vembL[l * 64 + 16 + m16] = o1;
          vembL[l * 64 + 32 + m16] = o2;
          vembL[l * 64 + 48 + m16] = o3;
        }
      }
    }
    __syncthreads();  // h32 writes + SST reads ordered before next layer's staging/SS writes
  }  // layers

  // ---- head: pool = vemb @ W_down + b_down; out = sigmoid(pool @ W_out + b_out)
  {
    float part = 0.f;
#pragma unroll
    for (int j2 = 0; j2 < 32; ++j2) {
      int j = wv * 32 + j2;
      part += vembL[j] * Wd[j * 64 + lane];
    }
    SS[wv * 64 + lane] = part;
    __syncthreads();
    if (wv == 0) {
      float acc = bd[lane];
#pragma unroll
      for (int w2 = 0; w2 < 8; ++w2) acc += SS[w2 * 64 + lane];
      float p = acc * Wo[lane];
      p = wave_red_sum(p);
      if (lane == 63) out[g] = 1.f / (1.f + expf(-(p + bo[0])));
    }
  }
}

extern "C" void kernel_launch(void* const* d_in, const int* in_sizes, int n_in,
                              void* d_out, int out_size, void* d_ws, size_t ws_size,
                              hipStream_t stream) {
  const float* x         = (const float*)d_in[0];
  const float* edge_attr = (const float*)d_in[1];
  const int*   ei        = (const int*)d_in[2];
  const float* W_node = (const float*)d_in[4];
  const float* b_node = (const float*)d_in[5];
  const float* W_edge = (const float*)d_in[6];
  const float* b_edge = (const float*)d_in[7];
  const float* Wq = (const float*)d_in[8];
  const float* bq = (const float*)d_in[9];
  const float* Wk = (const float*)d_in[10];
  const float* bk = (const float*)d_in[11];
  const float* Wv = (const float*)d_in[12];
  const float* bv = (const float*)d_in[13];
  const float* We = (const float*)d_in[14];
  const float* be = (const float*)d_in[15];
  const float* Wskip = (const float*)d_in[16];
  const float* bskip = (const float*)d_in[17];
  const float* W_down = (const float*)d_in[18];
  const float* b_down = (const float*)d_in[19];
  const float* W_out  = (const float*)d_in[20];
  const float* b_out  = (const float*)d_in[21];
  float* out = (float*)d_out;

  // workspace carve (~11.2 MB)
  float* p = (float*)d_ws;
  float* Gbuf  = p; p += 8192;
  float* bbuf  = p; p += 1024;
  float* bcatT = p; p += 16 * WC2;                  // 2304 floats
  unsigned short* WcatT = (unsigned short*)p; p += 16 * WC2 * 64 / 2;  // bf16, 294912 B
  int* offsB   = (int*)p; p += 256 * 129;           // 132 KB
  int* sortedSR = (int*)p; p += Ej;                 // 1.18 MB
  float* sortedEA = p; p += (size_t)Ej * 8;         // 9.44 MB

  k_prep2<<<36, 256, 0, stream>>>(We, be, W_edge, b_edge, Gbuf, bbuf);
  k_prepW<<<(16 * WC2 * 64) / 256, 256, 0, stream>>>(Wq, bq, Wk, bk, Wv, bv, Gbuf, bbuf,
                                                     WcatT, bcatT);
  k_sort<<<256, 256, 0, stream>>>(ei, edge_attr, sortedSR, sortedEA, offsB);
  k_fused<<<256, 512, 0, stream>>>(x, W_node, b_node, WcatT, bcatT,
                                   sortedSR, sortedEA, offsB,
                                   Gbuf, bbuf, Wskip, bskip, W_down, b_down, W_out, b_out,
                                   out);
}

// Round 15
// 427.221 us; speedup vs baseline: 2.8179x; 2.8179x over previous
//
#include <hip/hip_runtime.h>
#include <hip/hip_bf16.h>

constexpr int Ej  = 294912;  // total edges
constexpr int EPG = 1152;    // edges per graph
constexpr int WC2 = 144;     // fused-GEMM cols per head: A64 | V64 | r8:8 | cD | cS | pad6
constexpr int SPF = 132;     // scores fp32 row stride (floats); bf16 Wmat row lives at hw d*264
constexpr int HBS = 72;      // hB / A-matrix bf16 row stride (halfwords)
constexpr int VTS = 136;     // Vt bf16 row stride (halfwords)

typedef __attribute__((ext_vector_type(8))) short short8;   // 8 bf16 (MFMA A/B frag)
typedef __attribute__((ext_vector_type(4))) float f32x4;    // MFMA C/D frag

// fp32 -> bf16 bits, round-to-nearest-even
__device__ __forceinline__ unsigned short f2bf(float f) {
  unsigned u = __float_as_uint(f);
  u += 0x7FFFu + ((u >> 16) & 1u);
  return (unsigned short)(u >> 16);
}
__device__ __forceinline__ float bf2f(unsigned short b) {
  return __uint_as_float(((unsigned)b) << 16);
}
// DPP helpers: reductions within aligned 8-lane groups, pure VALU (no LDS pipe).
template <int CTRL>
__device__ __forceinline__ float dppf(float x) {
  return __int_as_float(__builtin_amdgcn_update_dpp(0, __float_as_int(x), CTRL, 0xf, 0xf, true));
}
// 0xB1 = quad_perm xor1, 0x4E = quad_perm xor2, 0x141 = row_half_mirror (i<->7-i in 8)
__device__ __forceinline__ float grp8_sum(float x) {
  x += dppf<0xB1>(x); x += dppf<0x4E>(x); x += dppf<0x141>(x); return x;
}
__device__ __forceinline__ float grp8_max(float x) {
  x = fmaxf(x, dppf<0xB1>(x)); x = fmaxf(x, dppf<0x4E>(x)); x = fmaxf(x, dppf<0x141>(x));
  return x;
}
// 64-lane sum via DPP. Result valid in lane 63.
__device__ __forceinline__ float wave_red_sum(float x) {
  x += __int_as_float(__builtin_amdgcn_update_dpp(0, __float_as_int(x), 0x111, 0xf, 0xf, true));
  x += __int_as_float(__builtin_amdgcn_update_dpp(0, __float_as_int(x), 0x112, 0xf, 0xf, true));
  x += __int_as_float(__builtin_amdgcn_update_dpp(0, __float_as_int(x), 0x114, 0xf, 0xf, true));
  x += __int_as_float(__builtin_amdgcn_update_dpp(0, __float_as_int(x), 0x118, 0xf, 0xf, true));
  x += __int_as_float(__builtin_amdgcn_update_dpp(0, __float_as_int(x), 0x142, 0xf, 0xf, true));
  x += __int_as_float(__builtin_amdgcn_update_dpp(0, __float_as_int(x), 0x143, 0xf, 0xf, true));
  return x;
}

// G[l][h][a][c] = sum_d W_edge[a,d]*We_l[d][h64+c];  bb[l][h][c] = be + b_edge@We
__global__ void k_prep2(const float* __restrict__ We, const float* __restrict__ be,
                        const float* __restrict__ W_edge, const float* __restrict__ b_edge,
                        float* __restrict__ G, float* __restrict__ bb) {
  int tid = blockIdx.x * 256 + threadIdx.x;  // 8192 + 1024
  if (tid < 8192) {
    int l = tid >> 11, rem = tid & 2047;
    int hh = rem >> 9, a = (rem >> 6) & 7, c = rem & 63;
    float acc = 0.f;
#pragma unroll 8
    for (int d = 0; d < 64; ++d)
      acc += W_edge[a * 64 + d] * We[l * 16384 + d * 256 + hh * 64 + c];
    G[tid] = acc;
  } else if (tid < 9216) {
    int t = tid - 8192;
    int l = t >> 8, rem = t & 255;
    int hh = rem >> 6, c = rem & 63;
    float acc = be[l * 256 + hh * 64 + c];
#pragma unroll 8
    for (int d = 0; d < 64; ++d)
      acc += b_edge[d] * We[l * 16384 + d * 256 + hh * 64 + c];
    bb[t] = acc;
  }
}

// WcatT [lh][col][kk] bf16 + bcatT fp32.  (see earlier rounds for column semantics)
__global__ void __launch_bounds__(256) k_prepW(
    const float* __restrict__ Wq, const float* __restrict__ bq,
    const float* __restrict__ Wk, const float* __restrict__ bk,
    const float* __restrict__ Wv, const float* __restrict__ bv,
    const float* __restrict__ Gbuf, const float* __restrict__ bbuf,
    unsigned short* __restrict__ WcatT, float* __restrict__ bcatT) {
  int t = blockIdx.x * 256 + threadIdx.x;  // 16*144*64
  if (t >= 16 * WC2 * 64) return;
  int kk = t & 63;
  int col = (t >> 6) % WC2;
  int lh = t / (WC2 * 64);
  int h = lh & 3, l = lh >> 2;
  const float* Wq_l = Wq + l * 16384;
  const float* Wk_l = Wk + l * 16384;
  const float* bq_l = bq + l * 256;
  const float* bk_l = bk + l * 256;
  float w = 0.f, bias = 0.f;
  if (col < 64) {
    float s = 0.f;
#pragma unroll 8
    for (int i = 0; i < 64; ++i)
      s += Wq_l[kk * 256 + h * 64 + i] * Wk_l[col * 256 + h * 64 + i];
    w = 0.125f * s;
  } else if (col < 128) {
    int j = col - 64;
    w = Wv[l * 16384 + kk * 256 + h * 64 + j];
    bias = bv[l * 256 + h * 64 + j];
  } else if (col < 136) {
    int a = col - 128;
    const float* Grow = Gbuf + l * 2048 + h * 512 + a * 64;
    float s = 0.f, sb = 0.f;
#pragma unroll 8
    for (int i = 0; i < 64; ++i) {
      s  += Wq_l[kk * 256 + h * 64 + i] * Grow[i];
      sb += bq_l[h * 64 + i] * Grow[i];
    }
    w = 0.125f * s; bias = 0.125f * sb;
  } else if (col == 136) {
    float s = 0.f, sb = 0.f;
#pragma unroll 8
    for (int i = 0; i < 64; ++i) {
      float bkb = bk_l[h * 64 + i] + bbuf[l * 256 + h * 64 + i];
      s  += Wq_l[kk * 256 + h * 64 + i] * bkb;
      sb += bq_l[h * 64 + i] * bkb;
    }
    w = 0.125f * s; bias = 0.125f * sb;
  } else if (col == 137) {
    float s = 0.f;
#pragma unroll 8
    for (int i = 0; i < 64; ++i)
      s += Wk_l[kk * 256 + h * 64 + i] * bq_l[h * 64 + i];
    w = 0.125f * s;
  }
  WcatT[(size_t)(lh * WC2 + col) * 64 + kk] = f2bf(w);
  if (kk == 0) bcatT[lh * WC2 + col] = bias;
}

// Sort each graph's edges by dst (dup-rank per (dst,src) via 16K cursor). Emits
// sortedSR (src | duprank<<8 | dst<<16), sortedEA, offs[g][129]. LDS 66 KB.
__global__ void __launch_bounds__(256) k_sort(const int* __restrict__ ei,
                                              const float* __restrict__ edge_attr,
                                              int* __restrict__ sortedSR,
                                              float* __restrict__ sortedEA,
                                              int* __restrict__ offs) {
  __shared__ unsigned cursor[16384];  // (dst,src) dup-rank, 64 KB
  __shared__ unsigned cnt[128];       // per-dst count -> scatter cursor
  __shared__ unsigned base[129];
  int g = blockIdx.x, tid = threadIdx.x;
  for (int i = tid; i < 16384; i += 256) cursor[i] = 0u;
  if (tid < 128) cnt[tid] = 0u;
  __syncthreads();
  for (int e = tid; e < EPG; e += 256) {
    int d = ei[Ej + g * EPG + e] - g * 128;
    atomicAdd(&cnt[d], 1u);
  }
  __syncthreads();
  if (tid == 0) {
    unsigned run = 0;
    for (int j = 0; j < 128; ++j) { base[j] = run; run += cnt[j]; }
    base[128] = run;
  }
  __syncthreads();
  if (tid < 128) { offs[g * 129 + tid] = (int)base[tid]; cnt[tid] = base[tid]; }
  if (tid == 0) offs[g * 129 + 128] = EPG;
  __syncthreads();
  for (int e = tid; e < EPG; e += 256) {
    int s = ei[g * EPG + e] - g * 128;
    int d = ei[Ej + g * EPG + e] - g * 128;
    unsigned pos = atomicAdd(&cnt[d], 1u);
    unsigned r = atomicAdd(&cursor[d * 128 + s], 1u);
    sortedSR[g * EPG + pos] = s | ((int)min(r, 3u) << 8) | (d << 16);
    const float4* ep = (const float4*)(edge_attr + ((size_t)g * EPG + e) * 8);
    float4* op = (float4*)(sortedEA + ((size_t)g * EPG + pos) * 8);
    op[0] = ep[0]; op[1] = ep[1];
  }
}

// One block per graph, 512 threads. __launch_bounds__(512, 1): rounds 11-14 showed the
// allocator pins VGPR=128 and SPILLS under (512,2) — the 2nd arg imposed a 128-reg cap
// while LDS (152KB) already limits us to 1 block/CU, so the cap bought nothing. With the
// cap lifted, edge_attr (10 slots x 8 f32 = 80 VGPR) is held in PERSISTENT REGISTERS
// (r13's design) -> PD has zero global traffic. 3 barriers/head. LDS 152576 B.
__global__ void __launch_bounds__(512, 1) k_fused(
    const float* __restrict__ x, const float* __restrict__ W_node, const float* __restrict__ b_node,
    const unsigned short* __restrict__ WcatT, const float* __restrict__ bcatT,
    const int* __restrict__ sortedSR, const float* __restrict__ sortedEA,
    const int* __restrict__ offs,
    const float* __restrict__ Gbuf, const float* __restrict__ bbuf,
    const float* __restrict__ Wskip, const float* __restrict__ bskip,
    const float* __restrict__ Wd, const float* __restrict__ bd,
    const float* __restrict__ Wo, const float* __restrict__ bo,
    float* __restrict__ out) {
  __shared__ float SS[128 * SPF];           // 67584 B: scores fp32 / Wmat bf16 (in-row) / Wskip
  __shared__ float h32[128 * 68];           // 34816 B: resident fp32 h
  __shared__ unsigned short hB[128 * HBS];  // 18432 B: bf16 h
  __shared__ unsigned short AV[128 * HBS];  // 18432 B: A-matrix (P0-P1) then Vt 64xVTS (PD-P5)
  __shared__ float r8L[128 * 8];            // 4096
  __shared__ float t8L[128 * 9];            // 4608
  __shared__ float sL[128];                 // 512
  __shared__ float cDL[128];                // 512
  __shared__ float cSL[128];                // 512
  __shared__ float GhL[512];                // 2048
  __shared__ float vembL[256];              // 1024

  int g = blockIdx.x, tid = threadIdx.x;
  int lane = tid & 63, m16 = lane & 15, quad = lane >> 4, wv = tid >> 6;  // wv 0..7
  const int m0 = wv * 16;  // this wave's m-strip / dst-strip everywhere
  const int gE = g * EPG;

  // node encoder -> h32
  for (int idx = tid; idx < 8192; idx += 512) {
    int n = idx >> 6, c = idx & 63;
    const float* xr = x + (size_t)(g * 128 + n) * 16;
    float acc = b_node[c];
#pragma unroll
    for (int d = 0; d < 16; ++d) acc += xr[d] * W_node[d * 64 + c];
    h32[n * 68 + c] = acc;
  }

  // per-dst segments: 8-lane group handles dsts dD0 and dD0+64
  const int dD0 = tid >> 3, sub = tid & 7;
  const int dD1 = dD0 + 64;
  const int ofs0 = offs[g * 129 + dD0];
  const int ofs1 = offs[g * 129 + dD1];
  const int dsw = (dD0 & 7) << 4;  // XOR swizzle; same for dD1
  // sortedSR + edge_attr are layer/head-invariant: load ONCE into persistent registers.
  // Clamped indices keep loads in-bounds; invalid slots hold finite garbage that is
  // neutralized by alpha=-inf selects / e=0 multiplies.
  int sr0_0, sr0_1, sr0_2, sr0_3, sr0_4, sr1_0, sr1_1, sr1_2, sr1_3, sr1_4;
  float4 ea00a, ea00b, ea01a, ea01b, ea02a, ea02b, ea03a, ea03b, ea04a, ea04b;
  float4 ea10a, ea10b, ea11a, ea11b, ea12a, ea12b, ea13a, ea13b, ea14a, ea14b;
  {
    int cnt0 = offs[g * 129 + dD0 + 1] - ofs0;
    int cnt1 = offs[g * 129 + dD1 + 1] - ofs1;
    int p = sub;
    int j00 = gE + min(ofs0 + p,      EPG - 1);
    int j01 = gE + min(ofs0 + p + 8,  EPG - 1);
    int j02 = gE + min(ofs0 + p + 16, EPG - 1);
    int j03 = gE + min(ofs0 + p + 24, EPG - 1);
    int j04 = gE + min(ofs0 + p + 32, EPG - 1);
    int j10 = gE + min(ofs1 + p,      EPG - 1);
    int j11 = gE + min(ofs1 + p + 8,  EPG - 1);
    int j12 = gE + min(ofs1 + p + 16, EPG - 1);
    int j13 = gE + min(ofs1 + p + 24, EPG - 1);
    int j14 = gE + min(ofs1 + p + 32, EPG - 1);
    sr0_0 = (p      < cnt0) ? sortedSR[j00] : -1;
    sr0_1 = (p + 8  < cnt0) ? sortedSR[j01] : -1;
    sr0_2 = (p + 16 < cnt0) ? sortedSR[j02] : -1;
    sr0_3 = (p + 24 < cnt0) ? sortedSR[j03] : -1;
    sr0_4 = (p + 32 < cnt0) ? sortedSR[j04] : -1;
    sr1_0 = (p      < cnt1) ? sortedSR[j10] : -1;
    sr1_1 = (p + 8  < cnt1) ? sortedSR[j11] : -1;
    sr1_2 = (p + 16 < cnt1) ? sortedSR[j12] : -1;
    sr1_3 = (p + 24 < cnt1) ? sortedSR[j13] : -1;
    sr1_4 = (p + 32 < cnt1) ? sortedSR[j14] : -1;
    ea00a = *(const float4*)(sortedEA + (size_t)j00 * 8);
    ea00b = *(const float4*)(sortedEA + (size_t)j00 * 8 + 4);
    ea01a = *(const float4*)(sortedEA + (size_t)j01 * 8);
    ea01b = *(const float4*)(sortedEA + (size_t)j01 * 8 + 4);
    ea02a = *(const float4*)(sortedEA + (size_t)j02 * 8);
    ea02b = *(const float4*)(sortedEA + (size_t)j02 * 8 + 4);
    ea03a = *(const float4*)(sortedEA + (size_t)j03 * 8);
    ea03b = *(const float4*)(sortedEA + (size_t)j03 * 8 + 4);
    ea04a = *(const float4*)(sortedEA + (size_t)j04 * 8);
    ea04b = *(const float4*)(sortedEA + (size_t)j04 * 8 + 4);
    ea10a = *(const float4*)(sortedEA + (size_t)j10 * 8);
    ea10b = *(const float4*)(sortedEA + (size_t)j10 * 8 + 4);
    ea11a = *(const float4*)(sortedEA + (size_t)j11 * 8);
    ea11b = *(const float4*)(sortedEA + (size_t)j11 * 8 + 4);
    ea12a = *(const float4*)(sortedEA + (size_t)j12 * 8);
    ea12b = *(const float4*)(sortedEA + (size_t)j12 * 8 + 4);
    ea13a = *(const float4*)(sortedEA + (size_t)j13 * 8);
    ea13b = *(const float4*)(sortedEA + (size_t)j13 * 8 + 4);
    ea14a = *(const float4*)(sortedEA + (size_t)j14 * 8);
    ea14b = *(const float4*)(sortedEA + (size_t)j14 * 8 + 4);
  }
  __syncthreads();

  for (int l = 0; l < 4; ++l) {
    // ---- stage hB = bf16(h32): 2 slices of 64 rows
    {
      int row = tid >> 3, c8 = tid & 7;
#pragma unroll
      for (int s2 = 0; s2 < 2; ++s2) {
        int rr = row + s2 * 64;
        const float* hr = &h32[rr * 68 + c8 * 8];
        float4 a0 = *(const float4*)hr, a1 = *(const float4*)(hr + 4);
        uint4 hp;
        hp.x = f2bf(a0.x) | ((unsigned)f2bf(a0.y) << 16);
        hp.y = f2bf(a0.z) | ((unsigned)f2bf(a0.w) << 16);
        hp.z = f2bf(a1.x) | ((unsigned)f2bf(a1.y) << 16);
        hp.w = f2bf(a1.z) | ((unsigned)f2bf(a1.w) << 16);
        *(uint4*)&hB[rr * HBS + c8 * 8] = hp;
      }
    }
    f32x4 accP5_0 = {0.f, 0.f, 0.f, 0.f};
    f32x4 accP5_1 = {0.f, 0.f, 0.f, 0.f};
    f32x4 accP5_2 = {0.f, 0.f, 0.f, 0.f};
    f32x4 accP5_3 = {0.f, 0.f, 0.f, 0.f};
    float4 wsk0, wsk1;
    __syncthreads();  // hB ready (stable for whole layer)

    for (int h = 0; h < 4; ++h) {
      const int lh = l * 4 + h;
      // ---- P0: qkv GEMM; WT/bias direct from global (L2-hot). 9 n-tiles per wave.
      const unsigned short* WTg = WcatT + (size_t)lh * (WC2 * 64);
      const float* bcTl = bcatT + (size_t)lh * WC2;
      f32x4 vf0, vf1, vf2, vf3;
      {
        const short8 ha0 = *(const short8*)&hB[(m0 + m16) * HBS + quad * 8];
        const short8 ha1 = *(const short8*)&hB[(m0 + m16) * HBS + 32 + quad * 8];
#pragma unroll
        for (int nt = 0; nt < 9; ++nt) {
          int n0 = nt * 16;
          const unsigned short* wb = WTg + (size_t)(n0 + m16) * 64 + quad * 8;
          const short8 b0 = *(const short8*)wb;
          const short8 b1 = *(const short8*)(wb + 32);
          float bias = bcTl[n0 + m16];
          f32x4 acc = {bias, bias, bias, bias};
          acc = __builtin_amdgcn_mfma_f32_16x16x32_bf16(ha0, b0, acc, 0, 0, 0);
          acc = __builtin_amdgcn_mfma_f32_16x16x32_bf16(ha1, b1, acc, 0, 0, 0);
          if (nt < 4) {
#pragma unroll
            for (int r = 0; r < 4; ++r)
              AV[(m0 + quad * 4 + r) * HBS + n0 + m16] = f2bf(acc[r]);
          } else if (nt == 4) {
            vf0 = acc;
          } else if (nt == 5) {
            vf1 = acc;
          } else if (nt == 6) {
            vf2 = acc;
          } else if (nt == 7) {
            vf3 = acc;
          } else {  // nt == 8: r8 | cD | cS
            if (m16 < 8) {
#pragma unroll
              for (int r = 0; r < 4; ++r) r8L[(m0 + quad * 4 + r) * 8 + m16] = acc[r];
            } else if (m16 == 8) {
#pragma unroll
              for (int r = 0; r < 4; ++r) cDL[m0 + quad * 4 + r] = acc[r];
            } else if (m16 == 9) {
#pragma unroll
              for (int r = 0; r < 4; ++r) cSL[m0 + quad * 4 + r] = acc[r];
            }
          }
        }
      }
      // NO barrier: P1 reads only own-wave AV rows (DS in-order) + stable hB.

      // ---- P1: scores MFMA -> SS (col XOR-swizzled) || GhL stage
      {
        GhL[tid] = Gbuf[l * 2048 + h * 512 + tid];
        const short8 sa0 = *(const short8*)&AV[(m0 + m16) * HBS + quad * 8];
        const short8 sa1 = *(const short8*)&AV[(m0 + m16) * HBS + 32 + quad * 8];
#pragma unroll
        for (int t = 0; t < 8; ++t) {
          int src0 = t * 16;
          const short8 b0 = *(const short8*)&hB[(src0 + m16) * HBS + quad * 8];
          const short8 b1 = *(const short8*)&hB[(src0 + m16) * HBS + 32 + quad * 8];
          f32x4 acc = {0.f, 0.f, 0.f, 0.f};
          acc = __builtin_amdgcn_mfma_f32_16x16x32_bf16(sa0, b0, acc, 0, 0, 0);
          acc = __builtin_amdgcn_mfma_f32_16x16x32_bf16(sa1, b1, acc, 0, 0, 0);
#pragma unroll
          for (int r = 0; r < 4; ++r) {
            int row = m0 + quad * 4 + r;
            SS[row * SPF + ((src0 + m16) ^ ((row & 7) << 4))] = acc[r];
          }
        }
      }
      __syncthreads();  // scores/cSL/r8L/cDL visible cross-wave for PD

      // ---- PD: V-deposit; two per-dst softmaxes; ea from PERSISTENT REGISTERS
      {
#pragma unroll
        for (int r = 0; r < 4; ++r) AV[(m16) * VTS + m0 + quad * 4 + r] = f2bf(vf0[r]);
#pragma unroll
        for (int r = 0; r < 4; ++r) AV[(16 + m16) * VTS + m0 + quad * 4 + r] = f2bf(vf1[r]);
#pragma unroll
        for (int r = 0; r < 4; ++r) AV[(32 + m16) * VTS + m0 + quad * 4 + r] = f2bf(vf2[r]);
#pragma unroll
        for (int r = 0; r < 4; ++r) AV[(48 + m16) * VTS + m0 + quad * 4 + r] = f2bf(vf3[r]);
        unsigned short* Wu = (unsigned short*)SS;

        // batched LDS loads (unpredicated; invalid slots read valid-but-unused addrs)
        int s00 = sr0_0 & 127, s01 = sr0_1 & 127, s02 = sr0_2 & 127, s03 = sr0_3 & 127,
            s04 = sr0_4 & 127;
        int s10 = sr1_0 & 127, s11 = sr1_1 & 127, s12 = sr1_2 & 127, s13 = sr1_3 & 127,
            s14 = sr1_4 & 127;
        float sc00 = SS[dD0 * SPF + (s00 ^ dsw)], sc01 = SS[dD0 * SPF + (s01 ^ dsw)],
              sc02 = SS[dD0 * SPF + (s02 ^ dsw)], sc03 = SS[dD0 * SPF + (s03 ^ dsw)],
              sc04 = SS[dD0 * SPF + (s04 ^ dsw)];
        float sc10 = SS[dD1 * SPF + (s10 ^ dsw)], sc11 = SS[dD1 * SPF + (s11 ^ dsw)],
              sc12 = SS[dD1 * SPF + (s12 ^ dsw)], sc13 = SS[dD1 * SPF + (s13 ^ dsw)],
              sc14 = SS[dD1 * SPF + (s14 ^ dsw)];
        float cs00 = cSL[s00], cs01 = cSL[s01], cs02 = cSL[s02], cs03 = cSL[s03],
              cs04 = cSL[s04];
        float cs10 = cSL[s10], cs11 = cSL[s11], cs12 = cSL[s12], cs13 = cSL[s13],
              cs14 = cSL[s14];
        float cD0 = cDL[dD0], cD1 = cDL[dD1];
        float4 r8a0 = *(const float4*)&r8L[dD0 * 8];
        float4 r8b0 = *(const float4*)&r8L[dD0 * 8 + 4];
        float4 r8a1 = *(const float4*)&r8L[dD1 * 8];
        float4 r8b1 = *(const float4*)&r8L[dD1 * 8 + 4];

        // pass A: dots from registers; validity via select
#define ADOT(AL, SR, EA_A, EA_B, SCV, CSV, CDV, R8A, R8B)                              \
        float AL;                                                                      \
        {                                                                              \
          float d = EA_A.x * R8A.x + EA_A.y * R8A.y + EA_A.z * R8A.z + EA_A.w * R8A.w  \
                  + EA_B.x * R8B.x + EA_B.y * R8B.y + EA_B.z * R8B.z + EA_B.w * R8B.w; \
          AL = (SR >= 0) ? (SCV + CDV + CSV + d) : -3.4e38f;                           \
        }
        ADOT(al00, sr0_0, ea00a, ea00b, sc00, cs00, cD0, r8a0, r8b0)
        ADOT(al01, sr0_1, ea01a, ea01b, sc01, cs01, cD0, r8a0, r8b0)
        ADOT(al02, sr0_2, ea02a, ea02b, sc02, cs02, cD0, r8a0, r8b0)
        ADOT(al03, sr0_3, ea03a, ea03b, sc03, cs03, cD0, r8a0, r8b0)
        ADOT(al04, sr0_4, ea04a, ea04b, sc04, cs04, cD0, r8a0, r8b0)
        ADOT(al10, sr1_0, ea10a, ea10b, sc10, cs10, cD1, r8a1, r8b1)
        ADOT(al11, sr1_1, ea11a, ea11b, sc11, cs11, cD1, r8a1, r8b1)
        ADOT(al12, sr1_2, ea12a, ea12b, sc12, cs12, cD1, r8a1, r8b1)
        ADOT(al13, sr1_3, ea13a, ea13b, sc13, cs13, cD1, r8a1, r8b1)
        ADOT(al14, sr1_4, ea14a, ea14b, sc14, cs14, cD1, r8a1, r8b1)
#undef ADOT
        float mx0 = grp8_max(fmaxf(fmaxf(fmaxf(al00, al01), fmaxf(al02, al03)), al04));
        float mx1 = grp8_max(fmaxf(fmaxf(fmaxf(al10, al11), fmaxf(al12, al13)), al14));

        // pass B: exp (select-zeroed) + t8 accumulation from registers (e=0 for invalid)
        float t8a0 = 0.f, t8a1 = 0.f, t8a2 = 0.f, t8a3 = 0.f, t8a4 = 0.f, t8a5 = 0.f,
              t8a6 = 0.f, t8a7 = 0.f;
        float t8b0 = 0.f, t8b1 = 0.f, t8b2 = 0.f, t8b3 = 0.f, t8b4 = 0.f, t8b5 = 0.f,
              t8b6 = 0.f, t8b7 = 0.f;
#define EXPT8(E, SR, EA_A, EA_B, AL, MX, T0, T1, T2, T3, T4, T5, T6, T7)               \
        float E = (SR >= 0) ? __expf(AL - MX) : 0.f;                                   \
        T0 += E * EA_A.x; T1 += E * EA_A.y; T2 += E * EA_A.z; T3 += E * EA_A.w;        \
        T4 += E * EA_B.x; T5 += E * EA_B.y; T6 += E * EA_B.z; T7 += E * EA_B.w;
        EXPT8(e00, sr0_0, ea00a, ea00b, al00, mx0, t8a0, t8a1, t8a2, t8a3, t8a4, t8a5, t8a6, t8a7)
        EXPT8(e01, sr0_1, ea01a, ea01b, al01, mx0, t8a0, t8a1, t8a2, t8a3, t8a4, t8a5, t8a6, t8a7)
        EXPT8(e02, sr0_2, ea02a, ea02b, al02, mx0, t8a0, t8a1, t8a2, t8a3, t8a4, t8a5, t8a6, t8a7)
        EXPT8(e03, sr0_3, ea03a, ea03b, al03, mx0, t8a0, t8a1, t8a2, t8a3, t8a4, t8a5, t8a6, t8a7)
        EXPT8(e04, sr0_4, ea04a, ea04b, al04, mx0, t8a0, t8a1, t8a2, t8a3, t8a4, t8a5, t8a6, t8a7)
        EXPT8(e10, sr1_0, ea10a, ea10b, al10, mx1, t8b0, t8b1, t8b2, t8b3, t8b4, t8b5, t8b6, t8b7)
        EXPT8(e11, sr1_1, ea11a, ea11b, al11, mx1, t8b0, t8b1, t8b2, t8b3, t8b4, t8b5, t8b6, t8b7)
        EXPT8(e12, sr1_2, ea12a, ea12b, al12, mx1, t8b0, t8b1, t8b2, t8b3, t8b4, t8b5, t8b6, t8b7)
        EXPT8(e13, sr1_3, ea13a, ea13b, al13, mx1, t8b0, t8b1, t8b2, t8b3, t8b4, t8b5, t8b6, t8b7)
        EXPT8(e14, sr1_4, ea14a, ea14b, al14, mx1, t8b0, t8b1, t8b2, t8b3, t8b4, t8b5, t8b6, t8b7)
#undef EXPT8
        float s0 = grp8_sum(e00 + e01 + e02 + e03 + e04);
        float s1 = grp8_sum(e10 + e11 + e12 + e13 + e14);
        t8a0 = grp8_sum(t8a0); t8a1 = grp8_sum(t8a1); t8a2 = grp8_sum(t8a2);
        t8a3 = grp8_sum(t8a3); t8a4 = grp8_sum(t8a4); t8a5 = grp8_sum(t8a5);
        t8a6 = grp8_sum(t8a6); t8a7 = grp8_sum(t8a7);
        t8b0 = grp8_sum(t8b0); t8b1 = grp8_sum(t8b1); t8b2 = grp8_sum(t8b2);
        t8b3 = grp8_sum(t8b3); t8b4 = grp8_sum(t8b4); t8b5 = grp8_sum(t8b5);
        t8b6 = grp8_sum(t8b6); t8b7 = grp8_sum(t8b7);
        float inv0 = 1.f / fmaxf(s0, 1e-16f);
        float inv1 = 1.f / fmaxf(s1, 1e-16f);

        // stores: t8L/sL, then zero rows, then scatter (DS in-order per wave)
        if (sub == 0) {
          t8L[dD0 * 9 + 0] = t8a0 * inv0; t8L[dD0 * 9 + 1] = t8a1 * inv0;
          t8L[dD0 * 9 + 2] = t8a2 * inv0; t8L[dD0 * 9 + 3] = t8a3 * inv0;
          t8L[dD0 * 9 + 4] = t8a4 * inv0; t8L[dD0 * 9 + 5] = t8a5 * inv0;
          t8L[dD0 * 9 + 6] = t8a6 * inv0; t8L[dD0 * 9 + 7] = t8a7 * inv0;
          sL[dD0] = s0;
          t8L[dD1 * 9 + 0] = t8b0 * inv1; t8L[dD1 * 9 + 1] = t8b1 * inv1;
          t8L[dD1 * 9 + 2] = t8b2 * inv1; t8L[dD1 * 9 + 3] = t8b3 * inv1;
          t8L[dD1 * 9 + 4] = t8b4 * inv1; t8L[dD1 * 9 + 5] = t8b5 * inv1;
          t8L[dD1 * 9 + 6] = t8b6 * inv1; t8L[dD1 * 9 + 7] = t8b7 * inv1;
          sL[dD1] = s1;
        }
        int rowb0 = dD0 * 264, rowb1 = dD1 * 264;
        int z0 = (sub * 16) ^ dsw;
        uint4 zz = make_uint4(0u, 0u, 0u, 0u);
        *(uint4*)&Wu[rowb0 + z0] = zz;
        *(uint4*)&Wu[rowb0 + z0 + 8] = zz;
        *(uint4*)&Wu[rowb1 + z0] = zz;
        *(uint4*)&Wu[rowb1 + z0 + 8] = zz;
        bool dup = false;
#define SCAT(SR, E, INV, ROWB)                                                         \
        if (SR >= 0) {                                                                 \
          int rk = (SR >> 8) & 3;                                                      \
          dup |= (rk != 0);                                                            \
          if (rk == 0) Wu[(ROWB) + (((SR) & 127) ^ dsw)] = f2bf((E) * (INV));          \
        }
        SCAT(sr0_0, e00, inv0, rowb0) SCAT(sr0_1, e01, inv0, rowb0)
        SCAT(sr0_2, e02, inv0, rowb0) SCAT(sr0_3, e03, inv0, rowb0)
        SCAT(sr0_4, e04, inv0, rowb0)
        SCAT(sr1_0, e10, inv1, rowb1) SCAT(sr1_1, e11, inv1, rowb1)
        SCAT(sr1_2, e12, inv1, rowb1) SCAT(sr1_3, e13, inv1, rowb1)
        SCAT(sr1_4, e14, inv1, rowb1)
#undef SCAT
        if (__any(dup)) {  // rare duplicate (dst,src): rank-ordered accumulate
#pragma unroll
          for (int rk = 1; rk < 4; ++rk) {
#define DUPA(SR, E, INV, ROWB)                                                         \
            if (SR >= 0 && (((SR >> 8) & 3) == rk)) {                                  \
              int sl = (ROWB) + (((SR) & 127) ^ dsw);                                  \
              Wu[sl] = f2bf(bf2f(Wu[sl]) + (E) * (INV));                               \
            }
            DUPA(sr0_0, e00, inv0, rowb0) DUPA(sr0_1, e01, inv0, rowb0)
            DUPA(sr0_2, e02, inv0, rowb0) DUPA(sr0_3, e03, inv0, rowb0)
            DUPA(sr0_4, e04, inv0, rowb0)
            DUPA(sr1_0, e10, inv1, rowb1) DUPA(sr1_1, e11, inv1, rowb1)
            DUPA(sr1_2, e12, inv1, rowb1) DUPA(sr1_3, e13, inv1, rowb1)
            DUPA(sr1_4, e14, inv1, rowb1)
#undef DUPA
          }
        }
      }
      __syncthreads();

      // ---- P5: accP5 += Wmat@Vt (MFMA, 4 col-tiles) + t8@G + (s>0)*bb
      {
        if (h == 3) {
          wsk0 = ((const float4*)(Wskip + (size_t)l * 4096))[tid];
          wsk1 = ((const float4*)(Wskip + (size_t)l * 4096))[512 + tid];
        }
        const unsigned short* Wu = (const unsigned short*)SS;
        int row0 = m0 + m16;
        short8 a_[4];
#pragma unroll
        for (int ks = 0; ks < 4; ++ks)
          a_[ks] = *(const short8*)&Wu[row0 * 264 + (((ks * 32) + quad * 8) ^ ((row0 & 7) << 4))];
#pragma unroll
        for (int t2 = 0; t2 < 4; ++t2) {
          int c0 = t2 * 16;
          f32x4 acc = (t2 == 0) ? accP5_0 : (t2 == 1) ? accP5_1 : (t2 == 2) ? accP5_2 : accP5_3;
#pragma unroll
          for (int ks = 0; ks < 4; ++ks) {
            const short8 b = *(const short8*)&AV[(c0 + m16) * VTS + ks * 32 + quad * 8];
            acc = __builtin_amdgcn_mfma_f32_16x16x32_bf16(a_[ks], b, acc, 0, 0, 0);
          }
          int col = c0 + m16;
          float bbv = bbuf[l * 256 + h * 64 + col];
          float gcol[8];
#pragma unroll
          for (int a8 = 0; a8 < 8; ++a8) gcol[a8] = GhL[a8 * 64 + col];
#pragma unroll
          for (int r = 0; r < 4; ++r) {
            int row = m0 + quad * 4 + r;
            float add = (sL[row] > 0.f) ? bbv : 0.f;
#pragma unroll
            for (int a8 = 0; a8 < 8; ++a8) add += t8L[row * 9 + a8] * gcol[a8];
            acc[r] += add;
          }
          if (t2 == 0) accP5_0 = acc;
          else if (t2 == 1) accP5_1 = acc;
          else if (t2 == 2) accP5_2 = acc;
          else accP5_3 = acc;
        }
      }
      __syncthreads();
    }  // heads

    // ---- update: out = 0.25*acc + h@Wskip+bskip ; vemb ; h += out (all in LDS)
    *(float4*)&SS[tid * 4] = wsk0;         // Wskip_l -> SS[0..2048)
    *(float4*)&SS[2048 + tid * 4] = wsk1;  // Wskip_l -> SS[2048..4096)
    __syncthreads();
    {
      float sk[4][4];
#pragma unroll
      for (int t2 = 0; t2 < 4; ++t2) {
        int col = t2 * 16 + m16;
        float bsv = bskip[l * 64 + col];
#pragma unroll
        for (int r = 0; r < 4; ++r) {
          int row = m0 + quad * 4 + r;
          float s = bsv;
#pragma unroll 8
          for (int d = 0; d < 64; ++d) s += h32[row * 68 + d] * SS[d * 64 + col];
          sk[t2][r] = s;
        }
      }
      __syncthreads();  // all h32 reads done before in-place writes
#pragma unroll
      for (int t2 = 0; t2 < 4; ++t2) {
        int col = t2 * 16 + m16;
#pragma unroll
        for (int r = 0; r < 4; ++r) {
          int row = m0 + quad * 4 + r;
          float av = (t2 == 0) ? accP5_0[r] : (t2 == 1) ? accP5_1[r]
                   : (t2 == 2) ? accP5_2[r] : accP5_3[r];
          float outv = av * 0.25f + sk[t2][r];
          float hnew = outv + h32[row * 68 + col];
          h32[row * 68 + col] = hnew;
          if (row == 127) vembL[l * 64 + col] = outv;
        }
      }
    }
    __syncthreads();
  }  // layers

  // ---- head: pool = vemb @ W_down + b_down; out = sigmoid(pool @ W_out + b_out)
  {
    float part = 0.f;
#pragma unroll
    for (int j2 = 0; j2 < 32; ++j2) {
      int j = wv * 32 + j2;
      part += vembL[j] * Wd[j * 64 + lane];
    }
    SS[wv * 64 + lane] = part;
    __syncthreads();
    if (wv == 0) {
      float acc = bd[lane];
#pragma unroll
      for (int w2 = 0; w2 < 8; ++w2) acc += SS[w2 * 64 + lane];
      float p = acc * Wo[lane];
      p = wave_red_sum(p);
      if (lane == 63) out[g] = 1.f / (1.f + expf(-(p + bo[0])));
    }
  }
}

extern "C" void kernel_launch(void* const* d_in, const int* in_sizes, int n_in,
                              void* d_out, int out_size, void* d_ws, size_t ws_size,
                              hipStream_t stream) {
  const float* x         = (const float*)d_in[0];
  const float* edge_attr = (const float*)d_in[1];
  const int*   ei        = (const int*)d_in[2];
  const float* W_node = (const float*)d_in[4];
  const float* b_node = (const float*)d_in[5];
  const float* W_edge = (const float*)d_in[6];
  const float* b_edge = (const float*)d_in[7];
  const float* Wq = (const float*)d_in[8];
  const float* bq = (const float*)d_in[9];
  const float* Wk = (const float*)d_in[10];
  const float* bk = (const float*)d_in[11];
  const float* Wv = (const float*)d_in[12];
  const float* bv = (const float*)d_in[13];
  const float* We = (const float*)d_in[14];
  const float* be = (const float*)d_in[15];
  const float* Wskip = (const float*)d_in[16];
  const float* bskip = (const float*)d_in[17];
  const float* W_down = (const float*)d_in[18];
  const float* b_down = (const float*)d_in[19];
  const float* W_out  = (const float*)d_in[20];
  const float* b_out  = (const float*)d_in[21];
  float* out = (float*)d_out;

  // workspace carve (~11.2 MB)
  float* p = (float*)d_ws;
  float* Gbuf  = p; p += 8192;
  float* bbuf  = p; p += 1024;
  float* bcatT = p; p += 16 * WC2;                  // 2304 floats
  unsigned short* WcatT = (unsigned short*)p; p += 16 * WC2 * 64 / 2;  // bf16, 294912 B
  int* offsB   = (int*)p; p += 256 * 129;           // 132 KB
  int* sortedSR = (int*)p; p += Ej;                 // 1.18 MB
  float* sortedEA = p; p += (size_t)Ej * 8;         // 9.44 MB

  k_prep2<<<36, 256, 0, stream>>>(We, be, W_edge, b_edge, Gbuf, bbuf);
  k_prepW<<<(16 * WC2 * 64) / 256, 256, 0, stream>>>(Wq, bq, Wk, bk, Wv, bv, Gbuf, bbuf,
                                                     WcatT, bcatT);
  k_sort<<<256, 256, 0, stream>>>(ei, edge_attr, sortedSR, sortedEA, offsB);
  k_fused<<<256, 512, 0, stream>>>(x, W_node, b_node, WcatT, bcatT,
                                   sortedSR, sortedEA, offsB,
                                   Gbuf, bbuf, Wskip, bskip, W_down, b_down, W_out, b_out,
                                   out);
}

// Round 16
// 376.665 us; speedup vs baseline: 3.1962x; 1.1342x over previous
//
#include <hip/hip_runtime.h>
#include <hip/hip_bf16.h>

constexpr int Ej  = 294912;  // total edges
constexpr int EPG = 1152;    // edges per graph
constexpr int WC2 = 144;     // fused-GEMM cols per head: A64 | V64 | r8:8 | cD | cS | pad6
constexpr int SPF = 132;     // scores fp32 row stride (floats); bf16 Wmat row lives at hw d*264
constexpr int HBS = 72;      // hB / A-matrix bf16 row stride (halfwords)
constexpr int VTS = 136;     // Vt bf16 row stride (halfwords)

typedef __attribute__((ext_vector_type(8))) short short8;   // 8 bf16 (MFMA A/B frag)
typedef __attribute__((ext_vector_type(4))) float f32x4;    // MFMA C/D frag

// fp32 -> bf16 bits, round-to-nearest-even
__device__ __forceinline__ unsigned short f2bf(float f) {
  unsigned u = __float_as_uint(f);
  u += 0x7FFFu + ((u >> 16) & 1u);
  return (unsigned short)(u >> 16);
}
__device__ __forceinline__ float bf2f(unsigned short b) {
  return __uint_as_float(((unsigned)b) << 16);
}
// DPP helpers: reductions within aligned 8-lane groups, pure VALU (no LDS pipe).
template <int CTRL>
__device__ __forceinline__ float dppf(float x) {
  return __int_as_float(__builtin_amdgcn_update_dpp(0, __float_as_int(x), CTRL, 0xf, 0xf, true));
}
// 0xB1 = quad_perm xor1, 0x4E = quad_perm xor2, 0x141 = row_half_mirror (i<->7-i in 8)
__device__ __forceinline__ float grp8_sum(float x) {
  x += dppf<0xB1>(x); x += dppf<0x4E>(x); x += dppf<0x141>(x); return x;
}
__device__ __forceinline__ float grp8_max(float x) {
  x = fmaxf(x, dppf<0xB1>(x)); x = fmaxf(x, dppf<0x4E>(x)); x = fmaxf(x, dppf<0x141>(x));
  return x;
}
// 64-lane sum via DPP. Result valid in lane 63.
__device__ __forceinline__ float wave_red_sum(float x) {
  x += __int_as_float(__builtin_amdgcn_update_dpp(0, __float_as_int(x), 0x111, 0xf, 0xf, true));
  x += __int_as_float(__builtin_amdgcn_update_dpp(0, __float_as_int(x), 0x112, 0xf, 0xf, true));
  x += __int_as_float(__builtin_amdgcn_update_dpp(0, __float_as_int(x), 0x114, 0xf, 0xf, true));
  x += __int_as_float(__builtin_amdgcn_update_dpp(0, __float_as_int(x), 0x118, 0xf, 0xf, true));
  x += __int_as_float(__builtin_amdgcn_update_dpp(0, __float_as_int(x), 0x142, 0xf, 0xf, true));
  x += __int_as_float(__builtin_amdgcn_update_dpp(0, __float_as_int(x), 0x143, 0xf, 0xf, true));
  return x;
}

// G[l][h][a][c] = sum_d W_edge[a,d]*We_l[d][h64+c];  bb[l][h][c] = be + b_edge@We
__global__ void k_prep2(const float* __restrict__ We, const float* __restrict__ be,
                        const float* __restrict__ W_edge, const float* __restrict__ b_edge,
                        float* __restrict__ G, float* __restrict__ bb) {
  int tid = blockIdx.x * 256 + threadIdx.x;  // 8192 + 1024
  if (tid < 8192) {
    int l = tid >> 11, rem = tid & 2047;
    int hh = rem >> 9, a = (rem >> 6) & 7, c = rem & 63;
    float acc = 0.f;
#pragma unroll 8
    for (int d = 0; d < 64; ++d)
      acc += W_edge[a * 64 + d] * We[l * 16384 + d * 256 + hh * 64 + c];
    G[tid] = acc;
  } else if (tid < 9216) {
    int t = tid - 8192;
    int l = t >> 8, rem = t & 255;
    int hh = rem >> 6, c = rem & 63;
    float acc = be[l * 256 + hh * 64 + c];
#pragma unroll 8
    for (int d = 0; d < 64; ++d)
      acc += b_edge[d] * We[l * 16384 + d * 256 + hh * 64 + c];
    bb[t] = acc;
  }
}

// WcatT [lh][col][kk] bf16 + bcatT fp32.  (see earlier rounds for column semantics)
__global__ void __launch_bounds__(256) k_prepW(
    const float* __restrict__ Wq, const float* __restrict__ bq,
    const float* __restrict__ Wk, const float* __restrict__ bk,
    const float* __restrict__ Wv, const float* __restrict__ bv,
    const float* __restrict__ Gbuf, const float* __restrict__ bbuf,
    unsigned short* __restrict__ WcatT, float* __restrict__ bcatT) {
  int t = blockIdx.x * 256 + threadIdx.x;  // 16*144*64
  if (t >= 16 * WC2 * 64) return;
  int kk = t & 63;
  int col = (t >> 6) % WC2;
  int lh = t / (WC2 * 64);
  int h = lh & 3, l = lh >> 2;
  const float* Wq_l = Wq + l * 16384;
  const float* Wk_l = Wk + l * 16384;
  const float* bq_l = bq + l * 256;
  const float* bk_l = bk + l * 256;
  float w = 0.f, bias = 0.f;
  if (col < 64) {
    float s = 0.f;
#pragma unroll 8
    for (int i = 0; i < 64; ++i)
      s += Wq_l[kk * 256 + h * 64 + i] * Wk_l[col * 256 + h * 64 + i];
    w = 0.125f * s;
  } else if (col < 128) {
    int j = col - 64;
    w = Wv[l * 16384 + kk * 256 + h * 64 + j];
    bias = bv[l * 256 + h * 64 + j];
  } else if (col < 136) {
    int a = col - 128;
    const float* Grow = Gbuf + l * 2048 + h * 512 + a * 64;
    float s = 0.f, sb = 0.f;
#pragma unroll 8
    for (int i = 0; i < 64; ++i) {
      s  += Wq_l[kk * 256 + h * 64 + i] * Grow[i];
      sb += bq_l[h * 64 + i] * Grow[i];
    }
    w = 0.125f * s; bias = 0.125f * sb;
  } else if (col == 136) {
    float s = 0.f, sb = 0.f;
#pragma unroll 8
    for (int i = 0; i < 64; ++i) {
      float bkb = bk_l[h * 64 + i] + bbuf[l * 256 + h * 64 + i];
      s  += Wq_l[kk * 256 + h * 64 + i] * bkb;
      sb += bq_l[h * 64 + i] * bkb;
    }
    w = 0.125f * s; bias = 0.125f * sb;
  } else if (col == 137) {
    float s = 0.f;
#pragma unroll 8
    for (int i = 0; i < 64; ++i)
      s += Wk_l[kk * 256 + h * 64 + i] * bq_l[h * 64 + i];
    w = 0.125f * s;
  }
  WcatT[(size_t)(lh * WC2 + col) * 64 + kk] = f2bf(w);
  if (kk == 0) bcatT[lh * WC2 + col] = bias;
}

// Sort each graph's edges by dst (dup-rank per (dst,src) via 16K cursor). Emits
// sortedSR (src | duprank<<8 | dst<<16), sortedEA, offs[g][129]. LDS 66 KB.
__global__ void __launch_bounds__(256) k_sort(const int* __restrict__ ei,
                                              const float* __restrict__ edge_attr,
                                              int* __restrict__ sortedSR,
                                              float* __restrict__ sortedEA,
                                              int* __restrict__ offs) {
  __shared__ unsigned cursor[16384];  // (dst,src) dup-rank, 64 KB
  __shared__ unsigned cnt[128];       // per-dst count -> scatter cursor
  __shared__ unsigned base[129];
  int g = blockIdx.x, tid = threadIdx.x;
  {
    uint4 zz = make_uint4(0u, 0u, 0u, 0u);
    for (int i = tid; i < 4096; i += 256) *(uint4*)&cursor[i * 4] = zz;
  }
  if (tid < 128) cnt[tid] = 0u;
  __syncthreads();
  for (int e = tid; e < EPG; e += 256) {
    int d = ei[Ej + g * EPG + e] - g * 128;
    atomicAdd(&cnt[d], 1u);
  }
  __syncthreads();
  if (tid == 0) {
    unsigned run = 0;
    for (int j = 0; j < 128; ++j) { base[j] = run; run += cnt[j]; }
    base[128] = run;
  }
  __syncthreads();
  if (tid < 128) { offs[g * 129 + tid] = (int)base[tid]; cnt[tid] = base[tid]; }
  if (tid == 0) offs[g * 129 + 128] = EPG;
  __syncthreads();
  for (int e = tid; e < EPG; e += 256) {
    int s = ei[g * EPG + e] - g * 128;
    int d = ei[Ej + g * EPG + e] - g * 128;
    unsigned pos = atomicAdd(&cnt[d], 1u);
    unsigned r = atomicAdd(&cursor[d * 128 + s], 1u);
    sortedSR[g * EPG + pos] = s | ((int)min(r, 3u) << 8) | (d << 16);
    const float4* ep = (const float4*)(edge_attr + ((size_t)g * EPG + e) * 8);
    float4* op = (float4*)(sortedEA + ((size_t)g * EPG + pos) * 8);
    op[0] = ep[0]; op[1] = ep[1];
  }
}

// One block per graph, 512 threads (8 waves, 2/SIMD, 256-reg budget). 3 barriers/head:
// P0 qkv GEMM (WT direct from global) -> P1 scores MFMA + GhL stage (NO barrier between:
// P1 reads only own-wave AV rows + stable hB) | B | PD per-dst softmax (inline dot(ea,r8),
// scalarized, DPP reductions, no atomics) | B | P5 Wmat@Vt MFMA + epilogue | B.
// VERIFIED OPTIMUM (round 10): 267us, VGPR=128, WRITE 3.6MB, zero spill. Rounds 11-15
// refuted: 1024-thr TLP (spills, VGPR pinned 64), unpredicated/clamped loads (spill),
// ea-in-registers (spill at the compiler's 128-reg heuristic cap under BOTH launch-bounds
// settings), LDS-vectorized update (worst spill). LDS 152576 B -> 1 block/CU.
__global__ void __launch_bounds__(512, 2) k_fused(
    const float* __restrict__ x, const float* __restrict__ W_node, const float* __restrict__ b_node,
    const unsigned short* __restrict__ WcatT, const float* __restrict__ bcatT,
    const int* __restrict__ sortedSR, const float* __restrict__ sortedEA,
    const int* __restrict__ offs,
    const float* __restrict__ Gbuf, const float* __restrict__ bbuf,
    const float* __restrict__ Wskip, const float* __restrict__ bskip,
    const float* __restrict__ Wd, const float* __restrict__ bd,
    const float* __restrict__ Wo, const float* __restrict__ bo,
    float* __restrict__ out) {
  __shared__ float SS[128 * SPF];           // 67584 B: scores fp32 / Wmat bf16 (in-row) / Wskip
  __shared__ float h32[128 * 68];           // 34816 B: resident fp32 h
  __shared__ unsigned short hB[128 * HBS];  // 18432 B: bf16 h
  __shared__ unsigned short AV[128 * HBS];  // 18432 B: A-matrix (P0-P1) then Vt 64xVTS (PD-P5)
  __shared__ float r8L[128 * 8];            // 4096
  __shared__ float t8L[128 * 9];            // 4608
  __shared__ float sL[128];                 // 512
  __shared__ float cDL[128];                // 512
  __shared__ float cSL[128];                // 512
  __shared__ float GhL[512];                // 2048
  __shared__ float vembL[256];              // 1024

  int g = blockIdx.x, tid = threadIdx.x;
  int lane = tid & 63, m16 = lane & 15, quad = lane >> 4, wv = tid >> 6;  // wv 0..7
  const int m0 = wv * 16;  // this wave's m-strip / dst-strip everywhere
  const int gE = g * EPG;

  // node encoder -> h32
  for (int idx = tid; idx < 8192; idx += 512) {
    int n = idx >> 6, c = idx & 63;
    const float* xr = x + (size_t)(g * 128 + n) * 16;
    float acc = b_node[c];
#pragma unroll
    for (int d = 0; d < 16; ++d) acc += xr[d] * W_node[d * 64 + c];
    h32[n * 68 + c] = acc;
  }

  // per-dst segments: 8-lane group handles dsts dD0 and dD0+64
  const int dD0 = tid >> 3, sub = tid & 7;
  const int dD1 = dD0 + 64;
  const int ofs0 = offs[g * 129 + dD0];
  const int ofs1 = offs[g * 129 + dD1];
  const int dsw = (dD0 & 7) << 4;  // XOR swizzle; same for dD1
  // sortedSR entries are layer/head-invariant: load ONCE into persistent named regs
  int sr0_0, sr0_1, sr0_2, sr0_3, sr0_4, sr1_0, sr1_1, sr1_2, sr1_3, sr1_4;
  {
    int cnt0 = offs[g * 129 + dD0 + 1] - ofs0;
    int cnt1 = offs[g * 129 + dD1 + 1] - ofs1;
    int p = sub;
    sr0_0 = (p      < cnt0) ? sortedSR[gE + ofs0 + p]      : -1;
    sr0_1 = (p + 8  < cnt0) ? sortedSR[gE + ofs0 + p + 8]  : -1;
    sr0_2 = (p + 16 < cnt0) ? sortedSR[gE + ofs0 + p + 16] : -1;
    sr0_3 = (p + 24 < cnt0) ? sortedSR[gE + ofs0 + p + 24] : -1;
    sr0_4 = (p + 32 < cnt0) ? sortedSR[gE + ofs0 + p + 32] : -1;
    sr1_0 = (p      < cnt1) ? sortedSR[gE + ofs1 + p]      : -1;
    sr1_1 = (p + 8  < cnt1) ? sortedSR[gE + ofs1 + p + 8]  : -1;
    sr1_2 = (p + 16 < cnt1) ? sortedSR[gE + ofs1 + p + 16] : -1;
    sr1_3 = (p + 24 < cnt1) ? sortedSR[gE + ofs1 + p + 24] : -1;
    sr1_4 = (p + 32 < cnt1) ? sortedSR[gE + ofs1 + p + 32] : -1;
  }
  __syncthreads();

  for (int l = 0; l < 4; ++l) {
    // ---- stage hB = bf16(h32): 2 slices of 64 rows
    {
      int row = tid >> 3, c8 = tid & 7;
#pragma unroll
      for (int s2 = 0; s2 < 2; ++s2) {
        int rr = row + s2 * 64;
        const float* hr = &h32[rr * 68 + c8 * 8];
        float4 a0 = *(const float4*)hr, a1 = *(const float4*)(hr + 4);
        uint4 hp;
        hp.x = f2bf(a0.x) | ((unsigned)f2bf(a0.y) << 16);
        hp.y = f2bf(a0.z) | ((unsigned)f2bf(a0.w) << 16);
        hp.z = f2bf(a1.x) | ((unsigned)f2bf(a1.y) << 16);
        hp.w = f2bf(a1.z) | ((unsigned)f2bf(a1.w) << 16);
        *(uint4*)&hB[rr * HBS + c8 * 8] = hp;
      }
    }
    f32x4 accP5_0 = {0.f, 0.f, 0.f, 0.f};
    f32x4 accP5_1 = {0.f, 0.f, 0.f, 0.f};
    f32x4 accP5_2 = {0.f, 0.f, 0.f, 0.f};
    f32x4 accP5_3 = {0.f, 0.f, 0.f, 0.f};
    float4 wsk0, wsk1;
    __syncthreads();  // hB ready (stable for whole layer)

    for (int h = 0; h < 4; ++h) {
      const int lh = l * 4 + h;
      // ---- P0: qkv GEMM; WT/bias direct from global (L2-hot). 9 n-tiles per wave.
      const unsigned short* WTg = WcatT + (size_t)lh * (WC2 * 64);
      const float* bcTl = bcatT + (size_t)lh * WC2;
      f32x4 vf0, vf1, vf2, vf3;
      {
        const short8 ha0 = *(const short8*)&hB[(m0 + m16) * HBS + quad * 8];
        const short8 ha1 = *(const short8*)&hB[(m0 + m16) * HBS + 32 + quad * 8];
#pragma unroll
        for (int nt = 0; nt < 9; ++nt) {
          int n0 = nt * 16;
          const unsigned short* wb = WTg + (size_t)(n0 + m16) * 64 + quad * 8;
          const short8 b0 = *(const short8*)wb;
          const short8 b1 = *(const short8*)(wb + 32);
          float bias = bcTl[n0 + m16];
          f32x4 acc = {bias, bias, bias, bias};
          acc = __builtin_amdgcn_mfma_f32_16x16x32_bf16(ha0, b0, acc, 0, 0, 0);
          acc = __builtin_amdgcn_mfma_f32_16x16x32_bf16(ha1, b1, acc, 0, 0, 0);
          if (nt < 4) {
#pragma unroll
            for (int r = 0; r < 4; ++r)
              AV[(m0 + quad * 4 + r) * HBS + n0 + m16] = f2bf(acc[r]);
          } else if (nt == 4) {
            vf0 = acc;
          } else if (nt == 5) {
            vf1 = acc;
          } else if (nt == 6) {
            vf2 = acc;
          } else if (nt == 7) {
            vf3 = acc;
          } else {  // nt == 8: r8 | cD | cS
            if (m16 < 8) {
#pragma unroll
              for (int r = 0; r < 4; ++r) r8L[(m0 + quad * 4 + r) * 8 + m16] = acc[r];
            } else if (m16 == 8) {
#pragma unroll
              for (int r = 0; r < 4; ++r) cDL[m0 + quad * 4 + r] = acc[r];
            } else if (m16 == 9) {
#pragma unroll
              for (int r = 0; r < 4; ++r) cSL[m0 + quad * 4 + r] = acc[r];
            }
          }
        }
      }
      // NO barrier: P1 reads only own-wave AV rows (DS in-order) + stable hB.

      // ---- P1: scores MFMA -> SS (col XOR-swizzled) || GhL stage
      {
        GhL[tid] = Gbuf[l * 2048 + h * 512 + tid];
        const short8 sa0 = *(const short8*)&AV[(m0 + m16) * HBS + quad * 8];
        const short8 sa1 = *(const short8*)&AV[(m0 + m16) * HBS + 32 + quad * 8];
#pragma unroll
        for (int t = 0; t < 8; ++t) {
          int src0 = t * 16;
          const short8 b0 = *(const short8*)&hB[(src0 + m16) * HBS + quad * 8];
          const short8 b1 = *(const short8*)&hB[(src0 + m16) * HBS + 32 + quad * 8];
          f32x4 acc = {0.f, 0.f, 0.f, 0.f};
          acc = __builtin_amdgcn_mfma_f32_16x16x32_bf16(sa0, b0, acc, 0, 0, 0);
          acc = __builtin_amdgcn_mfma_f32_16x16x32_bf16(sa1, b1, acc, 0, 0, 0);
#pragma unroll
          for (int r = 0; r < 4; ++r) {
            int row = m0 + quad * 4 + r;
            SS[row * SPF + ((src0 + m16) ^ ((row & 7) << 4))] = acc[r];
          }
        }
      }
      __syncthreads();  // scores/cSL/r8L/cDL visible cross-wave for PD

      // ---- PD: V-deposit; two per-dst softmaxes, scalarized, inline dot(ea,r8)
      {
#pragma unroll
        for (int r = 0; r < 4; ++r) AV[(m16) * VTS + m0 + quad * 4 + r] = f2bf(vf0[r]);
#pragma unroll
        for (int r = 0; r < 4; ++r) AV[(16 + m16) * VTS + m0 + quad * 4 + r] = f2bf(vf1[r]);
#pragma unroll
        for (int r = 0; r < 4; ++r) AV[(32 + m16) * VTS + m0 + quad * 4 + r] = f2bf(vf2[r]);
#pragma unroll
        for (int r = 0; r < 4; ++r) AV[(48 + m16) * VTS + m0 + quad * 4 + r] = f2bf(vf3[r]);
        unsigned short* Wu = (unsigned short*)SS;

        // batched LDS loads (unpredicated; invalid slots read valid-but-unused addrs)
        int s00 = sr0_0 & 127, s01 = sr0_1 & 127, s02 = sr0_2 & 127, s03 = sr0_3 & 127,
            s04 = sr0_4 & 127;
        int s10 = sr1_0 & 127, s11 = sr1_1 & 127, s12 = sr1_2 & 127, s13 = sr1_3 & 127,
            s14 = sr1_4 & 127;
        float sc00 = SS[dD0 * SPF + (s00 ^ dsw)], sc01 = SS[dD0 * SPF + (s01 ^ dsw)],
              sc02 = SS[dD0 * SPF + (s02 ^ dsw)], sc03 = SS[dD0 * SPF + (s03 ^ dsw)],
              sc04 = SS[dD0 * SPF + (s04 ^ dsw)];
        float sc10 = SS[dD1 * SPF + (s10 ^ dsw)], sc11 = SS[dD1 * SPF + (s11 ^ dsw)],
              sc12 = SS[dD1 * SPF + (s12 ^ dsw)], sc13 = SS[dD1 * SPF + (s13 ^ dsw)],
              sc14 = SS[dD1 * SPF + (s14 ^ dsw)];
        float cs00 = cSL[s00], cs01 = cSL[s01], cs02 = cSL[s02], cs03 = cSL[s03],
              cs04 = cSL[s04];
        float cs10 = cSL[s10], cs11 = cSL[s11], cs12 = cSL[s12], cs13 = cSL[s13],
              cs14 = cSL[s14];
        float cD0 = cDL[dD0], cD1 = cDL[dD1];
        float4 r8a0 = *(const float4*)&r8L[dD0 * 8];
        float4 r8b0 = *(const float4*)&r8L[dD0 * 8 + 4];
        float4 r8a1 = *(const float4*)&r8L[dD1 * 8];
        float4 r8b1 = *(const float4*)&r8L[dD1 * 8 + 4];

        // alphas: inline dot(ea, r8[dst]) with transient guarded ea loads
        float al00 = -3.4e38f, al01 = -3.4e38f, al02 = -3.4e38f, al03 = -3.4e38f,
              al04 = -3.4e38f;
        float al10 = -3.4e38f, al11 = -3.4e38f, al12 = -3.4e38f, al13 = -3.4e38f,
              al14 = -3.4e38f;
#define ADOT(AL, SR, OFS, IT, SCV, CSV, CDV, R8A, R8B)                                 \
        if (SR >= 0) {                                                                 \
          const float* ep = sortedEA + (size_t)(gE + (OFS) + sub + (IT)*8) * 8;        \
          float4 p0 = *(const float4*)ep;                                              \
          float4 p1 = *(const float4*)(ep + 4);                                        \
          AL = SCV + CDV + CSV                                                         \
             + p0.x * R8A.x + p0.y * R8A.y + p0.z * R8A.z + p0.w * R8A.w               \
             + p1.x * R8B.x + p1.y * R8B.y + p1.z * R8B.z + p1.w * R8B.w;              \
        }
        ADOT(al00, sr0_0, ofs0, 0, sc00, cs00, cD0, r8a0, r8b0)
        ADOT(al01, sr0_1, ofs0, 1, sc01, cs01, cD0, r8a0, r8b0)
        ADOT(al02, sr0_2, ofs0, 2, sc02, cs02, cD0, r8a0, r8b0)
        ADOT(al03, sr0_3, ofs0, 3, sc03, cs03, cD0, r8a0, r8b0)
        ADOT(al04, sr0_4, ofs0, 4, sc04, cs04, cD0, r8a0, r8b0)
        ADOT(al10, sr1_0, ofs1, 0, sc10, cs10, cD1, r8a1, r8b1)
        ADOT(al11, sr1_1, ofs1, 1, sc11, cs11, cD1, r8a1, r8b1)
        ADOT(al12, sr1_2, ofs1, 2, sc12, cs12, cD1, r8a1, r8b1)
        ADOT(al13, sr1_3, ofs1, 3, sc13, cs13, cD1, r8a1, r8b1)
        ADOT(al14, sr1_4, ofs1, 4, sc14, cs14, cD1, r8a1, r8b1)
#undef ADOT
        float mx0 = grp8_max(fmaxf(fmaxf(fmaxf(al00, al01), fmaxf(al02, al03)), al04));
        float mx1 = grp8_max(fmaxf(fmaxf(fmaxf(al10, al11), fmaxf(al12, al13)), al14));

        // exp + transient ea reload + unnormalized t8 accum (no LDS stores yet)
        float t8a0 = 0.f, t8a1 = 0.f, t8a2 = 0.f, t8a3 = 0.f, t8a4 = 0.f, t8a5 = 0.f,
              t8a6 = 0.f, t8a7 = 0.f;
        float t8b0 = 0.f, t8b1 = 0.f, t8b2 = 0.f, t8b3 = 0.f, t8b4 = 0.f, t8b5 = 0.f,
              t8b6 = 0.f, t8b7 = 0.f;
        float e00 = 0.f, e01 = 0.f, e02 = 0.f, e03 = 0.f, e04 = 0.f;
        float e10 = 0.f, e11 = 0.f, e12 = 0.f, e13 = 0.f, e14 = 0.f;
#define EXPT8(E, SR, OFS, IT, AL, MX, T0, T1, T2, T3, T4, T5, T6, T7)                  \
        if (SR >= 0) {                                                                 \
          E = __expf(AL - MX);                                                         \
          const float* ep = sortedEA + (size_t)(gE + (OFS) + sub + (IT)*8) * 8;        \
          float4 p0 = *(const float4*)ep;                                              \
          float4 p1 = *(const float4*)(ep + 4);                                        \
          T0 += E * p0.x; T1 += E * p0.y; T2 += E * p0.z; T3 += E * p0.w;              \
          T4 += E * p1.x; T5 += E * p1.y; T6 += E * p1.z; T7 += E * p1.w;              \
        }
        EXPT8(e00, sr0_0, ofs0, 0, al00, mx0, t8a0, t8a1, t8a2, t8a3, t8a4, t8a5, t8a6, t8a7)
        EXPT8(e01, sr0_1, ofs0, 1, al01, mx0, t8a0, t8a1, t8a2, t8a3, t8a4, t8a5, t8a6, t8a7)
        EXPT8(e02, sr0_2, ofs0, 2, al02, mx0, t8a0, t8a1, t8a2, t8a3, t8a4, t8a5, t8a6, t8a7)
        EXPT8(e03, sr0_3, ofs0, 3, al03, mx0, t8a0, t8a1, t8a2, t8a3, t8a4, t8a5, t8a6, t8a7)
        EXPT8(e04, sr0_4, ofs0, 4, al04, mx0, t8a0, t8a1, t8a2, t8a3, t8a4, t8a5, t8a6, t8a7)
        EXPT8(e10, sr1_0, ofs1, 0, al10, mx1, t8b0, t8b1, t8b2, t8b3, t8b4, t8b5, t8b6, t8b7)
        EXPT8(e11, sr1_1, ofs1, 1, al11, mx1, t8b0, t8b1, t8b2, t8b3, t8b4, t8b5, t8b6, t8b7)
        EXPT8(e12, sr1_2, ofs1, 2, al12, mx1, t8b0, t8b1, t8b2, t8b3, t8b4, t8b5, t8b6, t8b7)
        EXPT8(e13, sr1_3, ofs1, 3, al13, mx1, t8b0, t8b1, t8b2, t8b3, t8b4, t8b5, t8b6, t8b7)
        EXPT8(e14, sr1_4, ofs1, 4, al14, mx1, t8b0, t8b1, t8b2, t8b3, t8b4, t8b5, t8b6, t8b7)
#undef EXPT8
        float s0 = grp8_sum(e00 + e01 + e02 + e03 + e04);
        float s1 = grp8_sum(e10 + e11 + e12 + e13 + e14);
        t8a0 = grp8_sum(t8a0); t8a1 = grp8_sum(t8a1); t8a2 = grp8_sum(t8a2);
        t8a3 = grp8_sum(t8a3); t8a4 = grp8_sum(t8a4); t8a5 = grp8_sum(t8a5);
        t8a6 = grp8_sum(t8a6); t8a7 = grp8_sum(t8a7);
        t8b0 = grp8_sum(t8b0); t8b1 = grp8_sum(t8b1); t8b2 = grp8_sum(t8b2);
        t8b3 = grp8_sum(t8b3); t8b4 = grp8_sum(t8b4); t8b5 = grp8_sum(t8b5);
        t8b6 = grp8_sum(t8b6); t8b7 = grp8_sum(t8b7);
        float inv0 = 1.f / fmaxf(s0, 1e-16f);
        float inv1 = 1.f / fmaxf(s1, 1e-16f);

        // stores: t8L/sL, then zero rows, then scatter (DS in-order per wave)
        if (sub == 0) {
          t8L[dD0 * 9 + 0] = t8a0 * inv0; t8L[dD0 * 9 + 1] = t8a1 * inv0;
          t8L[dD0 * 9 + 2] = t8a2 * inv0; t8L[dD0 * 9 + 3] = t8a3 * inv0;
          t8L[dD0 * 9 + 4] = t8a4 * inv0; t8L[dD0 * 9 + 5] = t8a5 * inv0;
          t8L[dD0 * 9 + 6] = t8a6 * inv0; t8L[dD0 * 9 + 7] = t8a7 * inv0;
          sL[dD0] = s0;
          t8L[dD1 * 9 + 0] = t8b0 * inv1; t8L[dD1 * 9 + 1] = t8b1 * inv1;
          t8L[dD1 * 9 + 2] = t8b2 * inv1; t8L[dD1 * 9 + 3] = t8b3 * inv1;
          t8L[dD1 * 9 + 4] = t8b4 * inv1; t8L[dD1 * 9 + 5] = t8b5 * inv1;
          t8L[dD1 * 9 + 6] = t8b6 * inv1; t8L[dD1 * 9 + 7] = t8b7 * inv1;
          sL[dD1] = s1;
        }
        int rowb0 = dD0 * 264, rowb1 = dD1 * 264;
        int z0 = (sub * 16) ^ dsw;
        uint4 zz = make_uint4(0u, 0u, 0u, 0u);
        *(uint4*)&Wu[rowb0 + z0] = zz;
        *(uint4*)&Wu[rowb0 + z0 + 8] = zz;
        *(uint4*)&Wu[rowb1 + z0] = zz;
        *(uint4*)&Wu[rowb1 + z0 + 8] = zz;
        bool dup = false;
#define SCAT(SR, E, INV, ROWB)                                                         \
        if (SR >= 0) {                                                                 \
          int rk = (SR >> 8) & 3;                                                      \
          dup |= (rk != 0);                                                            \
          if (rk == 0) Wu[(ROWB) + (((SR) & 127) ^ dsw)] = f2bf((E) * (INV));          \
        }
        SCAT(sr0_0, e00, inv0, rowb0) SCAT(sr0_1, e01, inv0, rowb0)
        SCAT(sr0_2, e02, inv0, rowb0) SCAT(sr0_3, e03, inv0, rowb0)
        SCAT(sr0_4, e04, inv0, rowb0)
        SCAT(sr1_0, e10, inv1, rowb1) SCAT(sr1_1, e11, inv1, rowb1)
        SCAT(sr1_2, e12, inv1, rowb1) SCAT(sr1_3, e13, inv1, rowb1)
        SCAT(sr1_4, e14, inv1, rowb1)
#undef SCAT
        if (__any(dup)) {  // rare duplicate (dst,src): rank-ordered accumulate
#pragma unroll
          for (int rk = 1; rk < 4; ++rk) {
#define DUPA(SR, E, INV, ROWB)                                                         \
            if (SR >= 0 && (((SR >> 8) & 3) == rk)) {                                  \
              int sl = (ROWB) + (((SR) & 127) ^ dsw);                                  \
              Wu[sl] = f2bf(bf2f(Wu[sl]) + (E) * (INV));                               \
            }
            DUPA(sr0_0, e00, inv0, rowb0) DUPA(sr0_1, e01, inv0, rowb0)
            DUPA(sr0_2, e02, inv0, rowb0) DUPA(sr0_3, e03, inv0, rowb0)
            DUPA(sr0_4, e04, inv0, rowb0)
            DUPA(sr1_0, e10, inv1, rowb1) DUPA(sr1_1, e11, inv1, rowb1)
            DUPA(sr1_2, e12, inv1, rowb1) DUPA(sr1_3, e13, inv1, rowb1)
            DUPA(sr1_4, e14, inv1, rowb1)
#undef DUPA
          }
        }
      }
      __syncthreads();

      // ---- P5: accP5 += Wmat@Vt (MFMA, 4 col-tiles) + t8@G + (s>0)*bb
      {
        if (h == 3) {
          wsk0 = ((const float4*)(Wskip + (size_t)l * 4096))[tid];
          wsk1 = ((const float4*)(Wskip + (size_t)l * 4096))[512 + tid];
        }
        const unsigned short* Wu = (const unsigned short*)SS;
        int row0 = m0 + m16;
        short8 a_[4];
#pragma unroll
        for (int ks = 0; ks < 4; ++ks)
          a_[ks] = *(const short8*)&Wu[row0 * 264 + (((ks * 32) + quad * 8) ^ ((row0 & 7) << 4))];
#pragma unroll
        for (int t2 = 0; t2 < 4; ++t2) {
          int c0 = t2 * 16;
          f32x4 acc = (t2 == 0) ? accP5_0 : (t2 == 1) ? accP5_1 : (t2 == 2) ? accP5_2 : accP5_3;
#pragma unroll
          for (int ks = 0; ks < 4; ++ks) {
            const short8 b = *(const short8*)&AV[(c0 + m16) * VTS + ks * 32 + quad * 8];
            acc = __builtin_amdgcn_mfma_f32_16x16x32_bf16(a_[ks], b, acc, 0, 0, 0);
          }
          int col = c0 + m16;
          float bbv = bbuf[l * 256 + h * 64 + col];
          float gcol[8];
#pragma unroll
          for (int a8 = 0; a8 < 8; ++a8) gcol[a8] = GhL[a8 * 64 + col];
#pragma unroll
          for (int r = 0; r < 4; ++r) {
            int row = m0 + quad * 4 + r;
            float add = (sL[row] > 0.f) ? bbv : 0.f;
#pragma unroll
            for (int a8 = 0; a8 < 8; ++a8) add += t8L[row * 9 + a8] * gcol[a8];
            acc[r] += add;
          }
          if (t2 == 0) accP5_0 = acc;
          else if (t2 == 1) accP5_1 = acc;
          else if (t2 == 2) accP5_2 = acc;
          else accP5_3 = acc;
        }
      }
      __syncthreads();
    }  // heads

    // ---- update: out = 0.25*acc + h@Wskip+bskip ; vemb ; h += out (all in LDS)
    *(float4*)&SS[tid * 4] = wsk0;         // Wskip_l -> SS[0..2048)
    *(float4*)&SS[2048 + tid * 4] = wsk1;  // Wskip_l -> SS[2048..4096)
    __syncthreads();
    {
      float sk[4][4];
#pragma unroll
      for (int t2 = 0; t2 < 4; ++t2) {
        int col = t2 * 16 + m16;
        float bsv = bskip[l * 64 + col];
#pragma unroll
        for (int r = 0; r < 4; ++r) {
          int row = m0 + quad * 4 + r;
          float s = bsv;
#pragma unroll 8
          for (int d = 0; d < 64; ++d) s += h32[row * 68 + d] * SS[d * 64 + col];
          sk[t2][r] = s;
        }
      }
      __syncthreads();  // all h32 reads done before in-place writes
#pragma unroll
      for (int t2 = 0; t2 < 4; ++t2) {
        int col = t2 * 16 + m16;
#pragma unroll
        for (int r = 0; r < 4; ++r) {
          int row = m0 + quad * 4 + r;
          float av = (t2 == 0) ? accP5_0[r] : (t2 == 1) ? accP5_1[r]
                   : (t2 == 2) ? accP5_2[r] : accP5_3[r];
          float outv = av * 0.25f + sk[t2][r];
          float hnew = outv + h32[row * 68 + col];
          h32[row * 68 + col] = hnew;
          if (row == 127) vembL[l * 64 + col] = outv;
        }
      }
    }
    __syncthreads();
  }  // layers

  // ---- head: pool = vemb @ W_down + b_down; out = sigmoid(pool @ W_out + b_out)
  {
    float part = 0.f;
#pragma unroll
    for (int j2 = 0; j2 < 32; ++j2) {
      int j = wv * 32 + j2;
      part += vembL[j] * Wd[j * 64 + lane];
    }
    SS[wv * 64 + lane] = part;
    __syncthreads();
    if (wv == 0) {
      float acc = bd[lane];
#pragma unroll
      for (int w2 = 0; w2 < 8; ++w2) acc += SS[w2 * 64 + lane];
      float p = acc * Wo[lane];
      p = wave_red_sum(p);
      if (lane == 63) out[g] = 1.f / (1.f + expf(-(p + bo[0])));
    }
  }
}

extern "C" void kernel_launch(void* const* d_in, const int* in_sizes, int n_in,
                              void* d_out, int out_size, void* d_ws, size_t ws_size,
                              hipStream_t stream) {
  const float* x         = (const float*)d_in[0];
  const float* edge_attr = (const float*)d_in[1];
  const int*   ei        = (const int*)d_in[2];
  const float* W_node = (const float*)d_in[4];
  const float* b_node = (const float*)d_in[5];
  const float* W_edge = (const float*)d_in[6];
  const float* b_edge = (const float*)d_in[7];
  const float* Wq = (const float*)d_in[8];
  const float* bq = (const float*)d_in[9];
  const float* Wk = (const float*)d_in[10];
  const float* bk = (const float*)d_in[11];
  const float* Wv = (const float*)d_in[12];
  const float* bv = (const float*)d_in[13];
  const float* We = (const float*)d_in[14];
  const float* be = (const float*)d_in[15];
  const float* Wskip = (const float*)d_in[16];
  const float* bskip = (const float*)d_in[17];
  const float* W_down = (const float*)d_in[18];
  const float* b_down = (const float*)d_in[19];
  const float* W_out  = (const float*)d_in[20];
  const float* b_out  = (const float*)d_in[21];
  float* out = (float*)d_out;

  // workspace carve (~11.2 MB)
  float* p = (float*)d_ws;
  float* Gbuf  = p; p += 8192;
  float* bbuf  = p; p += 1024;
  float* bcatT = p; p += 16 * WC2;                  // 2304 floats
  unsigned short* WcatT = (unsigned short*)p; p += 16 * WC2 * 64 / 2;  // bf16, 294912 B
  int* offsB   = (int*)p; p += 256 * 129;           // 132 KB
  int* sortedSR = (int*)p; p += Ej;                 // 1.18 MB
  float* sortedEA = p; p += (size_t)Ej * 8;         // 9.44 MB

  k_prep2<<<36, 256, 0, stream>>>(We, be, W_edge, b_edge, Gbuf, bbuf);
  k_prepW<<<(16 * WC2 * 64) / 256, 256, 0, stream>>>(Wq, bq, Wk, bk, Wv, bv, Gbuf, bbuf,
                                                     WcatT, bcatT);
  k_sort<<<256, 256, 0, stream>>>(ei, edge_attr, sortedSR, sortedEA, offsB);
  k_fused<<<256, 512, 0, stream>>>(x, W_node, b_node, WcatT, bcatT,
                                   sortedSR, sortedEA, offsB,
                                   Gbuf, bbuf, Wskip, bskip, W_down, b_down, W_out, b_out,
                                   out);
}